// Round 10
// baseline (433.424 us; speedup 1.0000x reference)
//
#include <hip/hip_runtime.h>
#include <hip/hip_bf16.h>

// ---------------------------------------------------------------------------
// GCN forward on MI355X — round 10.
// R9 evidence: dense gather still latency-bound (VALU 25%, FETCH 58MB ~= 8 XCD
// x 6.4MB fp8 h + P stream): fp8 h EXCEEDS the 4MB/XCD L2. Fix: feature-split
// two-pass propagation — hH0/hH1 are 3.2MB each (L2-RESIDENT).
//   pass1: gather feats 0-31 from hH0, relu, store fp8 partial h2h0 (3.2MB)
//   pass2: gather feats 32-63 from hH1, relu, read h2h0, fused dense -> z fp8
// Row-half = 32B = 8 lanes -> 2 edges per load instr per 16-lane group
// (per-lane __shfl source sb+j+p). All P streams use nontemporal loads so
// they don't evict resident tables (W1/hH*/z).
// ---------------------------------------------------------------------------

#define HID 64
#define LAB 40
#define RSH 9          // 512 rows per bucket
#define KMAX 512       // max buckets (runtime K = 391)
#define TILE 4096      // elements per bucketA block

__device__ __forceinline__ float loadF(const void* p, size_t i, int bf16) {
    if (bf16) return __bfloat162float(((const __hip_bfloat16*)p)[i]);
    return ((const float*)p)[i];
}

__device__ __forceinline__ int loadI(const void* p, size_t i, int i64) {
    if (i64) return (int)(((const long long*)p)[i]);
    return ((const int*)p)[i];
}

// packed bf16x2 helpers
__device__ __forceinline__ float bflo(unsigned v) { return __uint_as_float(v << 16); }
__device__ __forceinline__ float bfhi(unsigned v) { return __uint_as_float(v & 0xFFFF0000u); }
__device__ __forceinline__ unsigned bfr16(float x) {
    unsigned u = __float_as_uint(x);
    return (u + 0x7FFFu + ((u >> 16) & 1u)) >> 16;
}
__device__ __forceinline__ unsigned bfpack(float lo, float hi) {
    return bfr16(lo) | (bfr16(hi) << 16);
}

// fp8 e4m3 HW converts
__device__ __forceinline__ unsigned fp8pack4(float a, float b, float c, float d) {
    int r = __builtin_amdgcn_cvt_pk_fp8_f32(a, b, 0, false);
    r = __builtin_amdgcn_cvt_pk_fp8_f32(c, d, r, true);
    return (unsigned)r;
}

// nontemporal int2 load (keep P streams out of L2)
__device__ __forceinline__ void ntload(const int2* P, int idx, int* c, float* w) {
    long long raw = __builtin_nontemporal_load((const long long*)P + idx);
    *c = (int)(unsigned)(raw & 0xFFFFFFFFll);
    *w = __int_as_float((int)(raw >> 32));
}

// dtype probe (validated R1-R9)
__global__ void probe_kernel(const void* b1p, const void* fidxp, int* flags) {
    if (threadIdx.x == 0 && blockIdx.x == 0) {
        const unsigned short* u = (const unsigned short*)b1p;
        int bf16 = 1;
        for (int i = 0; i < 64; i += 2)
            if ((unsigned short)(u[i] & 0x7FFF) >= 0x3E80) { bf16 = 0; break; }
        const int* ip = (const int*)fidxp;
        int i64 = 1;
        for (int i = 1; i < 128; i += 2)
            if (ip[i] != 0) { i64 = 0; break; }
        flags[0] = bf16; flags[1] = i64; flags[2] = 0; flags[3] = 0;
    }
}

__global__ void zero_kernel(int4* p, int n4) {
    int i = blockIdx.x * blockDim.x + threadIdx.x;
    if (i < n4) p[i] = make_int4(0, 0, 0, 0);
}

// W1 -> packed bf16 staging: entry i = features 4i..4i+3 (uint2)
__global__ void convw1_kernel(const void* W1, uint2* w1q, const int* flags, int ne) {
    int i = blockIdx.x * blockDim.x + threadIdx.x;
    if (i < ne) {
        float f0 = loadF(W1, (size_t)4 * i,     flags[0]);
        float f1 = loadF(W1, (size_t)4 * i + 1, flags[0]);
        float f2 = loadF(W1, (size_t)4 * i + 2, flags[0]);
        float f3 = loadF(W1, (size_t)4 * i + 3, flags[0]);
        w1q[i] = make_uint2(bfpack(f0, f1), bfpack(f2, f3));
    }
}

// LDS-privatized bucket histogram (grid-stride)
__global__ void histB_kernel(const void* fidx, const void* eidx, int* cntB,
                             const int* flags, int nnz, int nE, int N, int nb) {
    __shared__ int lh[KMAX];
    for (int t = threadIdx.x; t < KMAX; t += 256) lh[t] = 0;
    __syncthreads();
    const int i64 = flags[1];
    const int nT = nnz + nE;
    for (int i = blockIdx.x * 256 + threadIdx.x; i < nT; i += nb * 256) {
        int grow = (i < nnz) ? loadI(fidx, (size_t)i, i64)
                             : N + loadI(eidx, (size_t)(i - nnz), i64);
        atomicAdd(&lh[grow >> RSH], 1);
    }
    __syncthreads();
    for (int t = threadIdx.x; t < KMAX; t += 256) {
        int c = lh[t];
        if (c) atomicAdd(&cntB[t], c);
    }
}

// single-block exclusive scan of bucket counts -> bqstart + bq cursors
__global__ void scanB_kernel(const int* cntB, int* bqstart, int* bq, int K) {
    __shared__ int s[KMAX];
    int t = threadIdx.x;
    int x = (t < K) ? cntB[t] : 0;
    s[t] = x;
    __syncthreads();
    for (int off = 1; off < KMAX; off <<= 1) {
        int v = (t >= off) ? s[t - off] : 0;
        __syncthreads();
        s[t] += v;
        __syncthreads();
    }
    if (t < K) { int st = s[t] - x; bqstart[t] = st; bq[t] = st; }
}

// Pass A: bucket-grouped scatter into Q. pr packs (grow<<12)|rank.
__global__ void bucketA_kernel(const void* fidx, const void* fval,
                               const void* eidx, const void* ew,
                               const int* flags, int* bq, int2* Q,
                               int nnz, int nE, int N) {
    __shared__ int hist[KMAX];
    __shared__ int gbase[KMAX];
    __shared__ int pr[TILE];
    const int i64 = flags[1], bf16 = flags[0];
    const int nT = nnz + nE;
    const int base = blockIdx.x * TILE;
    for (int t = threadIdx.x; t < KMAX; t += 256) hist[t] = 0;
    __syncthreads();
#pragma unroll
    for (int k = 0; k < TILE / 256; k++) {
        int i = base + k * 256 + threadIdx.x;
        if (i < nT) {
            int grow = (i < nnz) ? loadI(fidx, (size_t)i, i64)
                                 : N + loadI(eidx, (size_t)(i - nnz), i64);
            int rank = atomicAdd(&hist[grow >> RSH], 1);
            pr[k * 256 + threadIdx.x] = (grow << 12) | rank;
        }
    }
    __syncthreads();
    for (int t = threadIdx.x; t < KMAX; t += 256) {
        int c = hist[t];
        gbase[t] = c ? atomicAdd(&bq[t], c) : 0;
    }
    __syncthreads();
#pragma unroll
    for (int k = 0; k < TILE / 256; k++) {
        int i = base + k * 256 + threadIdx.x;
        if (i < nT) {
            int c; float v;
            if (i < nnz) {
                c = loadI(fidx, (size_t)nnz + i, i64);
                v = loadF(fval, (size_t)i, bf16);
            } else {
                int j = i - nnz;
                c = loadI(eidx, (size_t)nE + j, i64);
                v = loadF(ew, (size_t)j, bf16);
            }
            int p = pr[k * 256 + threadIdx.x];
            int grow = p >> 12;
            int pos = gbase[grow >> RSH] + (p & 0xFFF);
            Q[pos] = make_int2(((grow & ((1 << RSH) - 1)) << 17) | c,
                               __float_as_int(v));
        }
    }
}

// Pass B: one 512-thread block per bucket; LDS row hist + scan -> rp segment,
// scatter to P with LDS rank cursors.
__global__ void bucketB_kernel(const int2* Q, const int* bqstart, int* rp,
                               int2* P, int nT, int K) {
    __shared__ int lh[1 << RSH];
    __shared__ int s[1 << RSH];
    __shared__ int lstart[1 << RSH];
    const int b = blockIdx.x;
    const int t = threadIdx.x;
    const int start = bqstart[b];
    const int end = (b == K - 1) ? nT : bqstart[b + 1];
    lh[t] = 0;
    __syncthreads();
    for (int i = start + t; i < end; i += 512)
        atomicAdd(&lh[((unsigned)Q[i].x) >> 17], 1);
    __syncthreads();
    int x = lh[t];
    s[t] = x;
    __syncthreads();
    for (int off = 1; off < (1 << RSH); off <<= 1) {
        int v = (t >= off) ? s[t - off] : 0;
        __syncthreads();
        s[t] += v;
        __syncthreads();
    }
    int rowstart = start + s[t] - x;
    rp[(b << RSH) + t] = rowstart;
    lstart[t] = rowstart;
    lh[t] = 0;
    __syncthreads();
    for (int i = start + t; i < end; i += 512) {
        int2 el = Q[i];
        int lr = ((unsigned)el.x) >> 17;
        int rank = atomicAdd(&lh[lr], 1);
        P[lstart[lr] + rank] = make_int2(el.x & 0x1FFFF, el.y);
    }
}

// 4 rows/wave feat gather; h stored as two fp8 half-arrays hH0/hH1 (3.2MB ea).
__global__ void gather_feat_kernel(const int* rp, const int2* P,
                                   const uint2* w1q, const void* b1,
                                   unsigned* hH0, unsigned* hH1,
                                   const int* flags, int N) {
    int bf16 = flags[0];
    int wave = (blockIdx.x * blockDim.x + threadIdx.x) >> 6;
    int lane = threadIdx.x & 63;
    int g = lane >> 4, gl = lane & 15;
    int row = 4 * wave + g;
    int s = 0, e = 0;
    if (row < N) { s = rp[row]; e = rp[row + 1]; }
    float a0 = loadF(b1, (size_t)4 * gl,     bf16);
    float a1 = loadF(b1, (size_t)4 * gl + 1, bf16);
    float a2 = loadF(b1, (size_t)4 * gl + 2, bf16);
    float a3 = loadF(b1, (size_t)4 * gl + 3, bf16);
    const int sb = g << 4;
    for (int base = s; base < e; base += 16) {
        int idx = base + gl;
        int cl = 0; float vl = 0.f;
        if (idx < e) ntload(P, idx, &cl, &vl);
        int cnt = min(16, e - base);
        int j = 0;
        for (; j + 4 <= cnt; j += 4) {
            int   c0 = __shfl(cl, sb + j),     c1 = __shfl(cl, sb + j + 1);
            int   c2 = __shfl(cl, sb + j + 2), c3 = __shfl(cl, sb + j + 3);
            float v0 = __shfl(vl, sb + j),     v1 = __shfl(vl, sb + j + 1);
            float v2 = __shfl(vl, sb + j + 2), v3 = __shfl(vl, sb + j + 3);
            uint2 u0 = w1q[c0 * 16 + gl];
            uint2 u1 = w1q[c1 * 16 + gl];
            uint2 u2 = w1q[c2 * 16 + gl];
            uint2 u3 = w1q[c3 * 16 + gl];
            a0 += v0 * bflo(u0.x); a1 += v0 * bfhi(u0.x);
            a2 += v0 * bflo(u0.y); a3 += v0 * bfhi(u0.y);
            a0 += v1 * bflo(u1.x); a1 += v1 * bfhi(u1.x);
            a2 += v1 * bflo(u1.y); a3 += v1 * bfhi(u1.y);
            a0 += v2 * bflo(u2.x); a1 += v2 * bfhi(u2.x);
            a2 += v2 * bflo(u2.y); a3 += v2 * bfhi(u2.y);
            a0 += v3 * bflo(u3.x); a1 += v3 * bfhi(u3.x);
            a2 += v3 * bflo(u3.y); a3 += v3 * bfhi(u3.y);
        }
        for (; j < cnt; j++) {
            int   c = __shfl(cl, sb + j);
            float v = __shfl(vl, sb + j);
            uint2 u = w1q[c * 16 + gl];
            a0 += v * bflo(u.x); a1 += v * bfhi(u.x);
            a2 += v * bflo(u.y); a3 += v * bfhi(u.y);
        }
    }
    if (row < N) {
        unsigned pk = fp8pack4(a0, a1, a2, a3);
        unsigned* dst = (gl < 8) ? hH0 : hH1;    // feats 0-31 vs 32-63
        dst[row * 8 + (gl & 7)] = pk;
    }
}

// Propagation pass 1: feats 0-31 from hH0 (3.2MB, L2-resident).
// Group: p=gl>>3 edge parity, fl=gl&7 feature dword; 2 edges per load instr.
__global__ void gather_edge_h0_kernel(const int* rp, const int2* P,
                                      const unsigned* hH0, unsigned* h2h0, int N) {
    int wave = (blockIdx.x * blockDim.x + threadIdx.x) >> 6;
    int lane = threadIdx.x & 63;
    int g = lane >> 4, gl = lane & 15;
    int p = gl >> 3, fl = gl & 7;
    int row = 4 * wave + g;
    int s = 0, e = 0;
    if (row < N) { s = rp[N + row]; e = rp[N + row + 1]; }
    float a0 = 0.f, a1 = 0.f, a2 = 0.f, a3 = 0.f;
    const int sb = g << 4;
    for (int base = s; base < e; base += 16) {
        int idx = base + gl;
        int cl = 0; float wl = 0.f;
        if (idx < e) ntload(P, idx, &cl, &wl);
        int cnt = min(16, e - base);
        int j = 0;
        for (; j + 8 <= cnt; j += 8) {       // 4 steps x 2 edges
            int   c0 = __shfl(cl, sb + j + p),     c1 = __shfl(cl, sb + j + 2 + p);
            int   c2 = __shfl(cl, sb + j + 4 + p), c3 = __shfl(cl, sb + j + 6 + p);
            float w0 = __shfl(wl, sb + j + p),     w1 = __shfl(wl, sb + j + 2 + p);
            float w2 = __shfl(wl, sb + j + 4 + p), w3 = __shfl(wl, sb + j + 6 + p);
            int u0 = (int)hH0[c0 * 8 + fl];
            int u1 = (int)hH0[c1 * 8 + fl];
            int u2 = (int)hH0[c2 * 8 + fl];
            int u3 = (int)hH0[c3 * 8 + fl];
            a0 += w0 * __builtin_amdgcn_cvt_f32_fp8(u0, 0);
            a1 += w0 * __builtin_amdgcn_cvt_f32_fp8(u0, 1);
            a2 += w0 * __builtin_amdgcn_cvt_f32_fp8(u0, 2);
            a3 += w0 * __builtin_amdgcn_cvt_f32_fp8(u0, 3);
            a0 += w1 * __builtin_amdgcn_cvt_f32_fp8(u1, 0);
            a1 += w1 * __builtin_amdgcn_cvt_f32_fp8(u1, 1);
            a2 += w1 * __builtin_amdgcn_cvt_f32_fp8(u1, 2);
            a3 += w1 * __builtin_amdgcn_cvt_f32_fp8(u1, 3);
            a0 += w2 * __builtin_amdgcn_cvt_f32_fp8(u2, 0);
            a1 += w2 * __builtin_amdgcn_cvt_f32_fp8(u2, 1);
            a2 += w2 * __builtin_amdgcn_cvt_f32_fp8(u2, 2);
            a3 += w2 * __builtin_amdgcn_cvt_f32_fp8(u2, 3);
            a0 += w3 * __builtin_amdgcn_cvt_f32_fp8(u3, 0);
            a1 += w3 * __builtin_amdgcn_cvt_f32_fp8(u3, 1);
            a2 += w3 * __builtin_amdgcn_cvt_f32_fp8(u3, 2);
            a3 += w3 * __builtin_amdgcn_cvt_f32_fp8(u3, 3);
        }
        for (; j < cnt; j += 2) {
            int   c = __shfl(cl, sb + min(j + p, cnt - 1));
            float w = (j + p < cnt) ? __shfl(wl, sb + j + p) : 0.f;
            int u = (int)hH0[c * 8 + fl];
            a0 += w * __builtin_amdgcn_cvt_f32_fp8(u, 0);
            a1 += w * __builtin_amdgcn_cvt_f32_fp8(u, 1);
            a2 += w * __builtin_amdgcn_cvt_f32_fp8(u, 2);
            a3 += w * __builtin_amdgcn_cvt_f32_fp8(u, 3);
        }
    }
    a0 += __shfl_xor(a0, 8); a1 += __shfl_xor(a1, 8);
    a2 += __shfl_xor(a2, 8); a3 += __shfl_xor(a3, 8);
    if (row < N && p == 0)
        h2h0[row * 8 + fl] = fp8pack4(fmaxf(a0, 0.f), fmaxf(a1, 0.f),
                                      fmaxf(a2, 0.f), fmaxf(a3, 0.f));
}

// Propagation pass 2: feats 32-63 from hH1 (L2-resident) + read h2h0 partial
// + fused dense -> z fp8.
__global__ void gather_edge_h1_dense_kernel(const int* rp, const int2* P,
                                            const unsigned* hH1,
                                            const unsigned* h2h0,
                                            const void* W2, const void* b2,
                                            unsigned short* zF8,
                                            const int* flags, int N) {
    __shared__ float sW[HID * LAB];
    __shared__ float sb_[LAB];
    int bf16 = flags[0];
    for (int i = threadIdx.x; i < HID * LAB; i += blockDim.x) sW[i] = loadF(W2, i, bf16);
    for (int i = threadIdx.x; i < LAB; i += blockDim.x)       sb_[i] = loadF(b2, i, bf16);
    __syncthreads();
    int wave = (blockIdx.x * blockDim.x + threadIdx.x) >> 6;
    int lane = threadIdx.x & 63;
    int g = lane >> 4, gl = lane & 15;
    int p = gl >> 3, fl = gl & 7;
    int row = 4 * wave + g;
    int s = 0, e = 0;
    if (row < N) { s = rp[N + row]; e = rp[N + row + 1]; }
    float a0 = 0.f, a1 = 0.f, a2 = 0.f, a3 = 0.f;
    const int sb = g << 4;
    for (int base = s; base < e; base += 16) {
        int idx = base + gl;
        int cl = 0; float wl = 0.f;
        if (idx < e) ntload(P, idx, &cl, &wl);
        int cnt = min(16, e - base);
        int j = 0;
        for (; j + 8 <= cnt; j += 8) {
            int   c0 = __shfl(cl, sb + j + p),     c1 = __shfl(cl, sb + j + 2 + p);
            int   c2 = __shfl(cl, sb + j + 4 + p), c3 = __shfl(cl, sb + j + 6 + p);
            float w0 = __shfl(wl, sb + j + p),     w1 = __shfl(wl, sb + j + 2 + p);
            float w2 = __shfl(wl, sb + j + 4 + p), w3 = __shfl(wl, sb + j + 6 + p);
            int u0 = (int)hH1[c0 * 8 + fl];
            int u1 = (int)hH1[c1 * 8 + fl];
            int u2 = (int)hH1[c2 * 8 + fl];
            int u3 = (int)hH1[c3 * 8 + fl];
            a0 += w0 * __builtin_amdgcn_cvt_f32_fp8(u0, 0);
            a1 += w0 * __builtin_amdgcn_cvt_f32_fp8(u0, 1);
            a2 += w0 * __builtin_amdgcn_cvt_f32_fp8(u0, 2);
            a3 += w0 * __builtin_amdgcn_cvt_f32_fp8(u0, 3);
            a0 += w1 * __builtin_amdgcn_cvt_f32_fp8(u1, 0);
            a1 += w1 * __builtin_amdgcn_cvt_f32_fp8(u1, 1);
            a2 += w1 * __builtin_amdgcn_cvt_f32_fp8(u1, 2);
            a3 += w1 * __builtin_amdgcn_cvt_f32_fp8(u1, 3);
            a0 += w2 * __builtin_amdgcn_cvt_f32_fp8(u2, 0);
            a1 += w2 * __builtin_amdgcn_cvt_f32_fp8(u2, 1);
            a2 += w2 * __builtin_amdgcn_cvt_f32_fp8(u2, 2);
            a3 += w2 * __builtin_amdgcn_cvt_f32_fp8(u2, 3);
            a0 += w3 * __builtin_amdgcn_cvt_f32_fp8(u3, 0);
            a1 += w3 * __builtin_amdgcn_cvt_f32_fp8(u3, 1);
            a2 += w3 * __builtin_amdgcn_cvt_f32_fp8(u3, 2);
            a3 += w3 * __builtin_amdgcn_cvt_f32_fp8(u3, 3);
        }
        for (; j < cnt; j += 2) {
            int   c = __shfl(cl, sb + min(j + p, cnt - 1));
            float w = (j + p < cnt) ? __shfl(wl, sb + j + p) : 0.f;
            int u = (int)hH1[c * 8 + fl];
            a0 += w * __builtin_amdgcn_cvt_f32_fp8(u, 0);
            a1 += w * __builtin_amdgcn_cvt_f32_fp8(u, 1);
            a2 += w * __builtin_amdgcn_cvt_f32_fp8(u, 2);
            a3 += w * __builtin_amdgcn_cvt_f32_fp8(u, 3);
        }
    }
    a0 += __shfl_xor(a0, 8); a1 += __shfl_xor(a1, 8);
    a2 += __shfl_xor(a2, 8); a3 += __shfl_xor(a3, 8);
    float r0 = fmaxf(a0, 0.f), r1 = fmaxf(a1, 0.f);
    float r2 = fmaxf(a2, 0.f), r3 = fmaxf(a3, 0.f);
    // read pass-1 half (already relu'd fp8): lane fl -> feats 4fl..4fl+3
    int ud = (int)h2h0[(size_t)((row < N) ? row : 0) * 8 + fl];
    float d0 = __builtin_amdgcn_cvt_f32_fp8(ud, 0);
    float d1 = __builtin_amdgcn_cvt_f32_fp8(ud, 1);
    float d2 = __builtin_amdgcn_cvt_f32_fp8(ud, 2);
    float d3 = __builtin_amdgcn_cvt_f32_fp8(ud, 3);
    // lane gl holds global feats 4gl..4gl+3: gl<8 -> half0 (d), gl>=8 -> half1 (r)
    float e0 = (gl < 8) ? d0 : r0;
    float e1 = (gl < 8) ? d1 : r1;
    float e2 = (gl < 8) ? d2 : r2;
    float e3 = (gl < 8) ? d3 : r3;
    int jj = (lane < LAB) ? lane : 0;
#pragma unroll
    for (int pass = 0; pass < 4; pass++) {
        int prow = 4 * wave + pass;
        float zacc = sb_[jj];
        int srcb = pass << 4;
#pragma unroll
        for (int k = 0; k < 16; k++) {
            float h0 = __shfl(e0, srcb + k);
            float h1 = __shfl(e1, srcb + k);
            float h2 = __shfl(e2, srcb + k);
            float h3 = __shfl(e3, srcb + k);
            zacc += h0 * sW[(4 * k) * LAB + jj] + h1 * sW[(4 * k + 1) * LAB + jj]
                  + h2 * sW[(4 * k + 2) * LAB + jj] + h3 * sW[(4 * k + 3) * LAB + jj];
        }
        float zn = __shfl(zacc, (lane + 1) & 63);
        if (lane < LAB && !(lane & 1) && prow < N) {
            int pk = __builtin_amdgcn_cvt_pk_fp8_f32(zacc, zn, 0, false);
            zF8[(prow * LAB + lane) >> 1] = (unsigned short)pk;
        }
    }
}

// 4 rows/wave: z2 = A@z (fp8, z 4MB ~L2-resident w/ nt P), fused log_softmax.
__global__ void gather_edge_lsm_kernel(const int* rp, const int2* P,
                                       const unsigned* zF8, void* out,
                                       const int* flags, int N) {
    int bf16 = flags[0];
    int wave = (blockIdx.x * blockDim.x + threadIdx.x) >> 6;
    int lane = threadIdx.x & 63;
    int g = lane >> 4, gl = lane & 15;
    int row = 4 * wave + g;
    int s = 0, e = 0;
    if (row < N) { s = rp[N + row]; e = rp[N + row + 1]; }
    float a0 = 0.f, a1 = 0.f, a2 = 0.f, a3 = 0.f;
    const int sb = g << 4;
    const int act = (gl < 10);
    for (int base = s; base < e; base += 16) {
        int idx = base + gl;
        int cl = 0; float wl = 0.f;
        if (idx < e) ntload(P, idx, &cl, &wl);
        int cnt = min(16, e - base);
        int j = 0;
        for (; j + 4 <= cnt; j += 4) {
            int   c0 = __shfl(cl, sb + j),     c1 = __shfl(cl, sb + j + 1);
            int   c2 = __shfl(cl, sb + j + 2), c3 = __shfl(cl, sb + j + 3);
            float w0 = __shfl(wl, sb + j),     w1 = __shfl(wl, sb + j + 1);
            float w2 = __shfl(wl, sb + j + 2), w3 = __shfl(wl, sb + j + 3);
            if (act) {
                int u0 = (int)zF8[c0 * 10 + gl];
                int u1 = (int)zF8[c1 * 10 + gl];
                int u2 = (int)zF8[c2 * 10 + gl];
                int u3 = (int)zF8[c3 * 10 + gl];
                a0 += w0 * __builtin_amdgcn_cvt_f32_fp8(u0, 0);
                a1 += w0 * __builtin_amdgcn_cvt_f32_fp8(u0, 1);
                a2 += w0 * __builtin_amdgcn_cvt_f32_fp8(u0, 2);
                a3 += w0 * __builtin_amdgcn_cvt_f32_fp8(u0, 3);
                a0 += w1 * __builtin_amdgcn_cvt_f32_fp8(u1, 0);
                a1 += w1 * __builtin_amdgcn_cvt_f32_fp8(u1, 1);
                a2 += w1 * __builtin_amdgcn_cvt_f32_fp8(u1, 2);
                a3 += w1 * __builtin_amdgcn_cvt_f32_fp8(u1, 3);
                a0 += w2 * __builtin_amdgcn_cvt_f32_fp8(u2, 0);
                a1 += w2 * __builtin_amdgcn_cvt_f32_fp8(u2, 1);
                a2 += w2 * __builtin_amdgcn_cvt_f32_fp8(u2, 2);
                a3 += w2 * __builtin_amdgcn_cvt_f32_fp8(u2, 3);
                a0 += w3 * __builtin_amdgcn_cvt_f32_fp8(u3, 0);
                a1 += w3 * __builtin_amdgcn_cvt_f32_fp8(u3, 1);
                a2 += w3 * __builtin_amdgcn_cvt_f32_fp8(u3, 2);
                a3 += w3 * __builtin_amdgcn_cvt_f32_fp8(u3, 3);
            }
        }
        for (; j < cnt; j++) {
            int   c = __shfl(cl, sb + j);
            float w = __shfl(wl, sb + j);
            if (act) {
                int u = (int)zF8[c * 10 + gl];
                a0 += w * __builtin_amdgcn_cvt_f32_fp8(u, 0);
                a1 += w * __builtin_amdgcn_cvt_f32_fp8(u, 1);
                a2 += w * __builtin_amdgcn_cvt_f32_fp8(u, 2);
                a3 += w * __builtin_amdgcn_cvt_f32_fp8(u, 3);
            }
        }
    }
    float m = act ? fmaxf(fmaxf(a0, a1), fmaxf(a2, a3)) : -INFINITY;
#pragma unroll
    for (int off = 8; off; off >>= 1) m = fmaxf(m, __shfl_xor(m, off));
    float es = act ? (__expf(a0 - m) + __expf(a1 - m) + __expf(a2 - m) + __expf(a3 - m)) : 0.f;
#pragma unroll
    for (int off = 8; off; off >>= 1) es += __shfl_xor(es, off);
    float lse = m + __logf(es);
    if (act && row < N) {
        float o0 = a0 - lse, o1 = a1 - lse, o2 = a2 - lse, o3 = a3 - lse;
        if (bf16) {
            ((uint2*)out)[(size_t)row * 10 + gl] =
                make_uint2(bfpack(o0, o1), bfpack(o2, o3));
        } else {
            float4 v = make_float4(o0, o1, o2, o3);
            ((float4*)out)[(size_t)row * 10 + gl] = v;
        }
    }
}

extern "C" void kernel_launch(void* const* d_in, const int* in_sizes, int n_in,
                              void* d_out, int out_size, void* d_ws, size_t ws_size,
                              hipStream_t stream) {
    const void* fidx = d_in[0];
    const void* fval = d_in[1];
    const void* eidx = d_in[2];
    const void* ew   = d_in[3];
    const void* W1   = d_in[4];
    const void* b1   = d_in[5];
    const void* W2   = d_in[6];
    const void* b2   = d_in[7];

    const int nnz = in_sizes[1];          // 2,500,000
    const int nW1 = in_sizes[4];          // 2048*64
    const int nE  = in_sizes[3];          // 1,700,000
    const int N   = out_size / LAB;       // 100,000
    const int M   = 2 * N;
    const int nT  = nnz + nE;
    const int K   = (M + (1 << RSH) - 1) >> RSH;   // 391 buckets

    auto align256 = [](size_t x) { return (x + 255) & ~(size_t)255; };
    char* ws = (char*)d_ws;
    size_t off = 0;
    int*   flags   = (int*)(ws + off);   off += 256;
    // front: hH0 | hH1 | h2h0 (each N*8 u32 = 3.2MB) | zF8 (N*40B = 4MB);
    // Q (int2, 33.6MB) overlays front and dies before gather_feat writes hH0.
    char*  front   = ws + off;
    unsigned* hH0  = (unsigned*)front;
    unsigned* hH1  = hH0 + (size_t)N * 8;
    unsigned* h2h0 = hH1 + (size_t)N * 8;
    unsigned short* zF8 = (unsigned short*)(h2h0 + (size_t)N * 8);
    size_t frontBytes = (size_t)N * (3 * 32 + 40);
    size_t qBytes     = (size_t)nT * 8;
    off += align256(frontBytes > qBytes ? frontBytes : qBytes);
    int2*  P       = (int2*)(ws + off);  off += align256((size_t)nT * 8);
    int*   rp      = (int*)(ws + off);   off += align256(((size_t)KMAX << RSH) * 4 + 16);
    uint2* w1q     = (uint2*)(ws + off); off += align256((size_t)nW1 * 2);
    int*   cntB    = (int*)(ws + off);   off += KMAX * 4;
    int*   bqstart = (int*)(ws + off);   off += KMAX * 4;
    int*   bq      = (int*)(ws + off);   off += KMAX * 4;
    int2*  Q       = (int2*)front;

    // 1. dtype probe
    probe_kernel<<<1, 64, 0, stream>>>(b1, fidx, flags);

    // 2. zero bucket histogram; stage W1 packed
    zero_kernel<<<1, 256, 0, stream>>>((int4*)cntB, KMAX / 4);
    convw1_kernel<<<(nW1 / 4 + 255) / 256, 256, 0, stream>>>(W1, w1q, flags, nW1 / 4);

    // 3. bucket histogram (LDS-privatized)
    const int HB = 1024;
    histB_kernel<<<HB, 256, 0, stream>>>(fidx, eidx, cntB, flags, nnz, nE, N, HB);

    // 4. bucket scan -> starts + cursors
    scanB_kernel<<<1, KMAX, 0, stream>>>(cntB, bqstart, bq, K);

    // 5. pass A: bucket-grouped scatter into Q
    bucketA_kernel<<<(nT + TILE - 1) / TILE, 256, 0, stream>>>(
        fidx, fval, eidx, ew, flags, bq, Q, nnz, nE, N);

    // 6. pass B: per-bucket row hist/scan in LDS, rp segment, scatter -> P
    bucketB_kernel<<<K, 512, 0, stream>>>(Q, bqstart, rp, P, nT, K);

    // 7. h = sparse_features @ W1 + b1 -> fp8 halves
    int nwaves = (N + 3) / 4;
    int gblocks = (int)(((size_t)nwaves * 64 + 255) / 256);
    gather_feat_kernel<<<gblocks, 256, 0, stream>>>(rp, P, w1q, b1, hH0, hH1, flags, N);

    // 8a. propagation pass 1 (feats 0-31, hH0 L2-resident)
    gather_edge_h0_kernel<<<gblocks, 256, 0, stream>>>(rp, P, hH0, h2h0, N);

    // 8b. propagation pass 2 (feats 32-63) + fused dense -> z fp8
    gather_edge_h1_dense_kernel<<<gblocks, 256, 0, stream>>>(rp, P, hH1, h2h0,
                                                             W2, b2, zF8, flags, N);

    // 9. out = log_softmax(A_norm @ z)
    gather_edge_lsm_kernel<<<gblocks, 256, 0, stream>>>(rp, P, (const unsigned*)zF8,
                                                        d_out, flags, N);
}

// Round 11
// 372.588 us; speedup vs baseline: 1.1633x; 1.1633x over previous
//
#include <hip/hip_runtime.h>
#include <hip/hip_bf16.h>

// ---------------------------------------------------------------------------
// GCN forward on MI355X — round 11.
// R10 evidence: h1_dense at 121us with FETCH only 23MB, VALU 25%, 6.4M LDS
// conflicts -> bound by the dense epilogue's LDS pipe (~256 bpermute + ~512
// ds_read per wave ~= measured 290K cycles), NOT by the gather. Fixes:
//  (1) single merged propagation pass (R9-style full-row gather), no epilogue:
//      relu + fp8 store of h2 (6.4MB).
//  (2) separate shuffle-free/LDS-free dense kernel: lane=label keeps its W2
//      column in 64 unrolled VGPRs; rows wave-uniform -> h2 row loads are
//      scalar broadcasts. ~512 MFLOP => ~8us.
//  (3) lsm unchanged (R10).
// ---------------------------------------------------------------------------

#define HID 64
#define LAB 40
#define RSH 9          // 512 rows per bucket
#define KMAX 512       // max buckets (runtime K = 391)
#define TILE 4096      // elements per bucketA block

__device__ __forceinline__ float loadF(const void* p, size_t i, int bf16) {
    if (bf16) return __bfloat162float(((const __hip_bfloat16*)p)[i]);
    return ((const float*)p)[i];
}

__device__ __forceinline__ int loadI(const void* p, size_t i, int i64) {
    if (i64) return (int)(((const long long*)p)[i]);
    return ((const int*)p)[i];
}

// packed bf16x2 helpers
__device__ __forceinline__ float bflo(unsigned v) { return __uint_as_float(v << 16); }
__device__ __forceinline__ float bfhi(unsigned v) { return __uint_as_float(v & 0xFFFF0000u); }
__device__ __forceinline__ unsigned bfr16(float x) {
    unsigned u = __float_as_uint(x);
    return (u + 0x7FFFu + ((u >> 16) & 1u)) >> 16;
}
__device__ __forceinline__ unsigned bfpack(float lo, float hi) {
    return bfr16(lo) | (bfr16(hi) << 16);
}

// fp8 e4m3 HW converts
__device__ __forceinline__ unsigned fp8pack4(float a, float b, float c, float d) {
    int r = __builtin_amdgcn_cvt_pk_fp8_f32(a, b, 0, false);
    r = __builtin_amdgcn_cvt_pk_fp8_f32(c, d, r, true);
    return (unsigned)r;
}

// nontemporal int2 load (keep P streams out of L2)
__device__ __forceinline__ void ntload(const int2* P, int idx, int* c, float* w) {
    long long raw = __builtin_nontemporal_load((const long long*)P + idx);
    *c = (int)(unsigned)(raw & 0xFFFFFFFFll);
    *w = __int_as_float((int)(raw >> 32));
}

// dtype probe (validated R1-R10)
__global__ void probe_kernel(const void* b1p, const void* fidxp, int* flags) {
    if (threadIdx.x == 0 && blockIdx.x == 0) {
        const unsigned short* u = (const unsigned short*)b1p;
        int bf16 = 1;
        for (int i = 0; i < 64; i += 2)
            if ((unsigned short)(u[i] & 0x7FFF) >= 0x3E80) { bf16 = 0; break; }
        const int* ip = (const int*)fidxp;
        int i64 = 1;
        for (int i = 1; i < 128; i += 2)
            if (ip[i] != 0) { i64 = 0; break; }
        flags[0] = bf16; flags[1] = i64; flags[2] = 0; flags[3] = 0;
    }
}

__global__ void zero_kernel(int4* p, int n4) {
    int i = blockIdx.x * blockDim.x + threadIdx.x;
    if (i < n4) p[i] = make_int4(0, 0, 0, 0);
}

// W1 -> packed bf16 staging: entry i = features 4i..4i+3 (uint2)
__global__ void convw1_kernel(const void* W1, uint2* w1q, const int* flags, int ne) {
    int i = blockIdx.x * blockDim.x + threadIdx.x;
    if (i < ne) {
        float f0 = loadF(W1, (size_t)4 * i,     flags[0]);
        float f1 = loadF(W1, (size_t)4 * i + 1, flags[0]);
        float f2 = loadF(W1, (size_t)4 * i + 2, flags[0]);
        float f3 = loadF(W1, (size_t)4 * i + 3, flags[0]);
        w1q[i] = make_uint2(bfpack(f0, f1), bfpack(f2, f3));
    }
}

// LDS-privatized bucket histogram (grid-stride)
__global__ void histB_kernel(const void* fidx, const void* eidx, int* cntB,
                             const int* flags, int nnz, int nE, int N, int nb) {
    __shared__ int lh[KMAX];
    for (int t = threadIdx.x; t < KMAX; t += 256) lh[t] = 0;
    __syncthreads();
    const int i64 = flags[1];
    const int nT = nnz + nE;
    for (int i = blockIdx.x * 256 + threadIdx.x; i < nT; i += nb * 256) {
        int grow = (i < nnz) ? loadI(fidx, (size_t)i, i64)
                             : N + loadI(eidx, (size_t)(i - nnz), i64);
        atomicAdd(&lh[grow >> RSH], 1);
    }
    __syncthreads();
    for (int t = threadIdx.x; t < KMAX; t += 256) {
        int c = lh[t];
        if (c) atomicAdd(&cntB[t], c);
    }
}

// single-block exclusive scan of bucket counts -> bqstart + bq cursors
__global__ void scanB_kernel(const int* cntB, int* bqstart, int* bq, int K) {
    __shared__ int s[KMAX];
    int t = threadIdx.x;
    int x = (t < K) ? cntB[t] : 0;
    s[t] = x;
    __syncthreads();
    for (int off = 1; off < KMAX; off <<= 1) {
        int v = (t >= off) ? s[t - off] : 0;
        __syncthreads();
        s[t] += v;
        __syncthreads();
    }
    if (t < K) { int st = s[t] - x; bqstart[t] = st; bq[t] = st; }
}

// Pass A: bucket-grouped scatter into Q. pr packs (grow<<12)|rank.
__global__ void bucketA_kernel(const void* fidx, const void* fval,
                               const void* eidx, const void* ew,
                               const int* flags, int* bq, int2* Q,
                               int nnz, int nE, int N) {
    __shared__ int hist[KMAX];
    __shared__ int gbase[KMAX];
    __shared__ int pr[TILE];
    const int i64 = flags[1], bf16 = flags[0];
    const int nT = nnz + nE;
    const int base = blockIdx.x * TILE;
    for (int t = threadIdx.x; t < KMAX; t += 256) hist[t] = 0;
    __syncthreads();
#pragma unroll
    for (int k = 0; k < TILE / 256; k++) {
        int i = base + k * 256 + threadIdx.x;
        if (i < nT) {
            int grow = (i < nnz) ? loadI(fidx, (size_t)i, i64)
                                 : N + loadI(eidx, (size_t)(i - nnz), i64);
            int rank = atomicAdd(&hist[grow >> RSH], 1);
            pr[k * 256 + threadIdx.x] = (grow << 12) | rank;
        }
    }
    __syncthreads();
    for (int t = threadIdx.x; t < KMAX; t += 256) {
        int c = hist[t];
        gbase[t] = c ? atomicAdd(&bq[t], c) : 0;
    }
    __syncthreads();
#pragma unroll
    for (int k = 0; k < TILE / 256; k++) {
        int i = base + k * 256 + threadIdx.x;
        if (i < nT) {
            int c; float v;
            if (i < nnz) {
                c = loadI(fidx, (size_t)nnz + i, i64);
                v = loadF(fval, (size_t)i, bf16);
            } else {
                int j = i - nnz;
                c = loadI(eidx, (size_t)nE + j, i64);
                v = loadF(ew, (size_t)j, bf16);
            }
            int p = pr[k * 256 + threadIdx.x];
            int grow = p >> 12;
            int pos = gbase[grow >> RSH] + (p & 0xFFF);
            Q[pos] = make_int2(((grow & ((1 << RSH) - 1)) << 17) | c,
                               __float_as_int(v));
        }
    }
}

// Pass B: one 512-thread block per bucket; LDS row hist + scan -> rp segment,
// scatter to P with LDS rank cursors.
__global__ void bucketB_kernel(const int2* Q, const int* bqstart, int* rp,
                               int2* P, int nT, int K) {
    __shared__ int lh[1 << RSH];
    __shared__ int s[1 << RSH];
    __shared__ int lstart[1 << RSH];
    const int b = blockIdx.x;
    const int t = threadIdx.x;
    const int start = bqstart[b];
    const int end = (b == K - 1) ? nT : bqstart[b + 1];
    lh[t] = 0;
    __syncthreads();
    for (int i = start + t; i < end; i += 512)
        atomicAdd(&lh[((unsigned)Q[i].x) >> 17], 1);
    __syncthreads();
    int x = lh[t];
    s[t] = x;
    __syncthreads();
    for (int off = 1; off < (1 << RSH); off <<= 1) {
        int v = (t >= off) ? s[t - off] : 0;
        __syncthreads();
        s[t] += v;
        __syncthreads();
    }
    int rowstart = start + s[t] - x;
    rp[(b << RSH) + t] = rowstart;
    lstart[t] = rowstart;
    lh[t] = 0;
    __syncthreads();
    for (int i = start + t; i < end; i += 512) {
        int2 el = Q[i];
        int lr = ((unsigned)el.x) >> 17;
        int rank = atomicAdd(&lh[lr], 1);
        P[lstart[lr] + rank] = make_int2(el.x & 0x1FFFF, el.y);
    }
}

// 4 rows/wave feat gather: h = b1 + sum v*W1[c], stored fp8 (row*16+gl dword).
__global__ void gather_feat_kernel(const int* rp, const int2* P,
                                   const uint2* w1q, const void* b1,
                                   unsigned* hF8, const int* flags, int N) {
    int bf16 = flags[0];
    int wave = (blockIdx.x * blockDim.x + threadIdx.x) >> 6;
    int lane = threadIdx.x & 63;
    int g = lane >> 4, gl = lane & 15;
    int row = 4 * wave + g;
    int s = 0, e = 0;
    if (row < N) { s = rp[row]; e = rp[row + 1]; }
    float a0 = loadF(b1, (size_t)4 * gl,     bf16);
    float a1 = loadF(b1, (size_t)4 * gl + 1, bf16);
    float a2 = loadF(b1, (size_t)4 * gl + 2, bf16);
    float a3 = loadF(b1, (size_t)4 * gl + 3, bf16);
    const int sb = g << 4;
    for (int base = s; base < e; base += 16) {
        int idx = base + gl;
        int cl = 0; float vl = 0.f;
        if (idx < e) ntload(P, idx, &cl, &vl);
        int cnt = min(16, e - base);
        int j = 0;
        for (; j + 4 <= cnt; j += 4) {
            int   c0 = __shfl(cl, sb + j),     c1 = __shfl(cl, sb + j + 1);
            int   c2 = __shfl(cl, sb + j + 2), c3 = __shfl(cl, sb + j + 3);
            float v0 = __shfl(vl, sb + j),     v1 = __shfl(vl, sb + j + 1);
            float v2 = __shfl(vl, sb + j + 2), v3 = __shfl(vl, sb + j + 3);
            uint2 u0 = w1q[c0 * 16 + gl];
            uint2 u1 = w1q[c1 * 16 + gl];
            uint2 u2 = w1q[c2 * 16 + gl];
            uint2 u3 = w1q[c3 * 16 + gl];
            a0 += v0 * bflo(u0.x); a1 += v0 * bfhi(u0.x);
            a2 += v0 * bflo(u0.y); a3 += v0 * bfhi(u0.y);
            a0 += v1 * bflo(u1.x); a1 += v1 * bfhi(u1.x);
            a2 += v1 * bflo(u1.y); a3 += v1 * bfhi(u1.y);
            a0 += v2 * bflo(u2.x); a1 += v2 * bfhi(u2.x);
            a2 += v2 * bflo(u2.y); a3 += v2 * bfhi(u2.y);
            a0 += v3 * bflo(u3.x); a1 += v3 * bfhi(u3.x);
            a2 += v3 * bflo(u3.y); a3 += v3 * bfhi(u3.y);
        }
        for (; j < cnt; j++) {
            int   c = __shfl(cl, sb + j);
            float v = __shfl(vl, sb + j);
            uint2 u = w1q[c * 16 + gl];
            a0 += v * bflo(u.x); a1 += v * bfhi(u.x);
            a2 += v * bflo(u.y); a3 += v * bfhi(u.y);
        }
    }
    if (row < N) hF8[row * 16 + gl] = fp8pack4(a0, a1, a2, a3);
}

// Merged propagation, NO epilogue: h2 = relu(A @ h), fp8 in / fp8 out.
// 4 rows/wave, unroll 8 (R9 loop).
__global__ void gather_edge_h2_kernel(const int* rp, const int2* P,
                                      const unsigned* hF8, unsigned* h2F8,
                                      int N) {
    int wave = (blockIdx.x * blockDim.x + threadIdx.x) >> 6;
    int lane = threadIdx.x & 63;
    int g = lane >> 4, gl = lane & 15;
    int row = 4 * wave + g;
    int s = 0, e = 0;
    if (row < N) { s = rp[N + row]; e = rp[N + row + 1]; }
    float a0 = 0.f, a1 = 0.f, a2 = 0.f, a3 = 0.f;
    const int sb = g << 4;
    for (int base = s; base < e; base += 16) {
        int idx = base + gl;
        int cl = 0; float wl = 0.f;
        if (idx < e) ntload(P, idx, &cl, &wl);
        int cnt = min(16, e - base);
        int j = 0;
        for (; j + 8 <= cnt; j += 8) {
            int   c0 = __shfl(cl, sb + j),     c1 = __shfl(cl, sb + j + 1);
            int   c2 = __shfl(cl, sb + j + 2), c3 = __shfl(cl, sb + j + 3);
            int   c4 = __shfl(cl, sb + j + 4), c5 = __shfl(cl, sb + j + 5);
            int   c6 = __shfl(cl, sb + j + 6), c7 = __shfl(cl, sb + j + 7);
            float w0 = __shfl(wl, sb + j),     w1 = __shfl(wl, sb + j + 1);
            float w2 = __shfl(wl, sb + j + 2), w3 = __shfl(wl, sb + j + 3);
            float w4 = __shfl(wl, sb + j + 4), w5 = __shfl(wl, sb + j + 5);
            float w6 = __shfl(wl, sb + j + 6), w7 = __shfl(wl, sb + j + 7);
            int u0 = (int)hF8[c0 * 16 + gl];
            int u1 = (int)hF8[c1 * 16 + gl];
            int u2 = (int)hF8[c2 * 16 + gl];
            int u3 = (int)hF8[c3 * 16 + gl];
            int u4 = (int)hF8[c4 * 16 + gl];
            int u5 = (int)hF8[c5 * 16 + gl];
            int u6 = (int)hF8[c6 * 16 + gl];
            int u7 = (int)hF8[c7 * 16 + gl];
            a0 += w0 * __builtin_amdgcn_cvt_f32_fp8(u0, 0);
            a1 += w0 * __builtin_amdgcn_cvt_f32_fp8(u0, 1);
            a2 += w0 * __builtin_amdgcn_cvt_f32_fp8(u0, 2);
            a3 += w0 * __builtin_amdgcn_cvt_f32_fp8(u0, 3);
            a0 += w1 * __builtin_amdgcn_cvt_f32_fp8(u1, 0);
            a1 += w1 * __builtin_amdgcn_cvt_f32_fp8(u1, 1);
            a2 += w1 * __builtin_amdgcn_cvt_f32_fp8(u1, 2);
            a3 += w1 * __builtin_amdgcn_cvt_f32_fp8(u1, 3);
            a0 += w2 * __builtin_amdgcn_cvt_f32_fp8(u2, 0);
            a1 += w2 * __builtin_amdgcn_cvt_f32_fp8(u2, 1);
            a2 += w2 * __builtin_amdgcn_cvt_f32_fp8(u2, 2);
            a3 += w2 * __builtin_amdgcn_cvt_f32_fp8(u2, 3);
            a0 += w3 * __builtin_amdgcn_cvt_f32_fp8(u3, 0);
            a1 += w3 * __builtin_amdgcn_cvt_f32_fp8(u3, 1);
            a2 += w3 * __builtin_amdgcn_cvt_f32_fp8(u3, 2);
            a3 += w3 * __builtin_amdgcn_cvt_f32_fp8(u3, 3);
            a0 += w4 * __builtin_amdgcn_cvt_f32_fp8(u4, 0);
            a1 += w4 * __builtin_amdgcn_cvt_f32_fp8(u4, 1);
            a2 += w4 * __builtin_amdgcn_cvt_f32_fp8(u4, 2);
            a3 += w4 * __builtin_amdgcn_cvt_f32_fp8(u4, 3);
            a0 += w5 * __builtin_amdgcn_cvt_f32_fp8(u5, 0);
            a1 += w5 * __builtin_amdgcn_cvt_f32_fp8(u5, 1);
            a2 += w5 * __builtin_amdgcn_cvt_f32_fp8(u5, 2);
            a3 += w5 * __builtin_amdgcn_cvt_f32_fp8(u5, 3);
            a0 += w6 * __builtin_amdgcn_cvt_f32_fp8(u6, 0);
            a1 += w6 * __builtin_amdgcn_cvt_f32_fp8(u6, 1);
            a2 += w6 * __builtin_amdgcn_cvt_f32_fp8(u6, 2);
            a3 += w6 * __builtin_amdgcn_cvt_f32_fp8(u6, 3);
            a0 += w7 * __builtin_amdgcn_cvt_f32_fp8(u7, 0);
            a1 += w7 * __builtin_amdgcn_cvt_f32_fp8(u7, 1);
            a2 += w7 * __builtin_amdgcn_cvt_f32_fp8(u7, 2);
            a3 += w7 * __builtin_amdgcn_cvt_f32_fp8(u7, 3);
        }
        for (; j < cnt; j++) {
            int   c = __shfl(cl, sb + j);
            float w = __shfl(wl, sb + j);
            int u = (int)hF8[c * 16 + gl];
            a0 += w * __builtin_amdgcn_cvt_f32_fp8(u, 0);
            a1 += w * __builtin_amdgcn_cvt_f32_fp8(u, 1);
            a2 += w * __builtin_amdgcn_cvt_f32_fp8(u, 2);
            a3 += w * __builtin_amdgcn_cvt_f32_fp8(u, 3);
        }
    }
    if (row < N)
        h2F8[row * 16 + gl] = fp8pack4(fmaxf(a0, 0.f), fmaxf(a1, 0.f),
                                       fmaxf(a2, 0.f), fmaxf(a3, 0.f));
}

// Shuffle-free, LDS-free dense: z = relu_h2 @ W2 + b2, fp8 out.
// lane = label (40 active); W2 column in 64 unrolled VGPRs; rows wave-uniform
// -> h2 row loads become scalar broadcasts.
__global__ void dense_kernel(const unsigned* h2F8, const void* W2, const void* b2,
                             unsigned char* zb, const int* flags, int N) {
    int bf16 = flags[0];
    int wave = (int)((blockIdx.x * blockDim.x + threadIdx.x) >> 6);
    int lane = threadIdx.x & 63;
    int jj = (lane < LAB) ? lane : 0;
    float w2c[HID];
#pragma unroll
    for (int k = 0; k < HID; k++) w2c[k] = loadF(W2, (size_t)k * LAB + jj, bf16);
    float bias = loadF(b2, (size_t)jj, bf16);
    int r0 = wave * 32;
    int r1 = min(r0 + 32, N);
    for (int r = r0; r < r1; r++) {
        const unsigned* hr = h2F8 + (size_t)r * 16;
        float acc = bias;
#pragma unroll
        for (int k16 = 0; k16 < 16; k16++) {
            int d = (int)hr[k16];
            acc += __builtin_amdgcn_cvt_f32_fp8(d, 0) * w2c[4 * k16];
            acc += __builtin_amdgcn_cvt_f32_fp8(d, 1) * w2c[4 * k16 + 1];
            acc += __builtin_amdgcn_cvt_f32_fp8(d, 2) * w2c[4 * k16 + 2];
            acc += __builtin_amdgcn_cvt_f32_fp8(d, 3) * w2c[4 * k16 + 3];
        }
        if (lane < LAB) {
            int pk = __builtin_amdgcn_cvt_pk_fp8_f32(acc, acc, 0, false);
            zb[(size_t)r * LAB + lane] = (unsigned char)(pk & 0xFF);
        }
    }
}

// 4 rows/wave: z2 = A@z (fp8 gather), fused log_softmax -> out.
__global__ void gather_edge_lsm_kernel(const int* rp, const int2* P,
                                       const unsigned* zF8, void* out,
                                       const int* flags, int N) {
    int bf16 = flags[0];
    int wave = (blockIdx.x * blockDim.x + threadIdx.x) >> 6;
    int lane = threadIdx.x & 63;
    int g = lane >> 4, gl = lane & 15;
    int row = 4 * wave + g;
    int s = 0, e = 0;
    if (row < N) { s = rp[N + row]; e = rp[N + row + 1]; }
    float a0 = 0.f, a1 = 0.f, a2 = 0.f, a3 = 0.f;
    const int sb = g << 4;
    const int act = (gl < 10);
    for (int base = s; base < e; base += 16) {
        int idx = base + gl;
        int cl = 0; float wl = 0.f;
        if (idx < e) ntload(P, idx, &cl, &wl);
        int cnt = min(16, e - base);
        int j = 0;
        for (; j + 4 <= cnt; j += 4) {
            int   c0 = __shfl(cl, sb + j),     c1 = __shfl(cl, sb + j + 1);
            int   c2 = __shfl(cl, sb + j + 2), c3 = __shfl(cl, sb + j + 3);
            float w0 = __shfl(wl, sb + j),     w1 = __shfl(wl, sb + j + 1);
            float w2 = __shfl(wl, sb + j + 2), w3 = __shfl(wl, sb + j + 3);
            if (act) {
                int u0 = (int)zF8[c0 * 10 + gl];
                int u1 = (int)zF8[c1 * 10 + gl];
                int u2 = (int)zF8[c2 * 10 + gl];
                int u3 = (int)zF8[c3 * 10 + gl];
                a0 += w0 * __builtin_amdgcn_cvt_f32_fp8(u0, 0);
                a1 += w0 * __builtin_amdgcn_cvt_f32_fp8(u0, 1);
                a2 += w0 * __builtin_amdgcn_cvt_f32_fp8(u0, 2);
                a3 += w0 * __builtin_amdgcn_cvt_f32_fp8(u0, 3);
                a0 += w1 * __builtin_amdgcn_cvt_f32_fp8(u1, 0);
                a1 += w1 * __builtin_amdgcn_cvt_f32_fp8(u1, 1);
                a2 += w1 * __builtin_amdgcn_cvt_f32_fp8(u1, 2);
                a3 += w1 * __builtin_amdgcn_cvt_f32_fp8(u1, 3);
                a0 += w2 * __builtin_amdgcn_cvt_f32_fp8(u2, 0);
                a1 += w2 * __builtin_amdgcn_cvt_f32_fp8(u2, 1);
                a2 += w2 * __builtin_amdgcn_cvt_f32_fp8(u2, 2);
                a3 += w2 * __builtin_amdgcn_cvt_f32_fp8(u2, 3);
                a0 += w3 * __builtin_amdgcn_cvt_f32_fp8(u3, 0);
                a1 += w3 * __builtin_amdgcn_cvt_f32_fp8(u3, 1);
                a2 += w3 * __builtin_amdgcn_cvt_f32_fp8(u3, 2);
                a3 += w3 * __builtin_amdgcn_cvt_f32_fp8(u3, 3);
            }
        }
        for (; j < cnt; j++) {
            int   c = __shfl(cl, sb + j);
            float w = __shfl(wl, sb + j);
            if (act) {
                int u = (int)zF8[c * 10 + gl];
                a0 += w * __builtin_amdgcn_cvt_f32_fp8(u, 0);
                a1 += w * __builtin_amdgcn_cvt_f32_fp8(u, 1);
                a2 += w * __builtin_amdgcn_cvt_f32_fp8(u, 2);
                a3 += w * __builtin_amdgcn_cvt_f32_fp8(u, 3);
            }
        }
    }
    float m = act ? fmaxf(fmaxf(a0, a1), fmaxf(a2, a3)) : -INFINITY;
#pragma unroll
    for (int off = 8; off; off >>= 1) m = fmaxf(m, __shfl_xor(m, off));
    float es = act ? (__expf(a0 - m) + __expf(a1 - m) + __expf(a2 - m) + __expf(a3 - m)) : 0.f;
#pragma unroll
    for (int off = 8; off; off >>= 1) es += __shfl_xor(es, off);
    float lse = m + __logf(es);
    if (act && row < N) {
        float o0 = a0 - lse, o1 = a1 - lse, o2 = a2 - lse, o3 = a3 - lse;
        if (bf16) {
            ((uint2*)out)[(size_t)row * 10 + gl] =
                make_uint2(bfpack(o0, o1), bfpack(o2, o3));
        } else {
            float4 v = make_float4(o0, o1, o2, o3);
            ((float4*)out)[(size_t)row * 10 + gl] = v;
        }
    }
}

extern "C" void kernel_launch(void* const* d_in, const int* in_sizes, int n_in,
                              void* d_out, int out_size, void* d_ws, size_t ws_size,
                              hipStream_t stream) {
    const void* fidx = d_in[0];
    const void* fval = d_in[1];
    const void* eidx = d_in[2];
    const void* ew   = d_in[3];
    const void* W1   = d_in[4];
    const void* b1   = d_in[5];
    const void* W2   = d_in[6];
    const void* b2   = d_in[7];

    const int nnz = in_sizes[1];          // 2,500,000
    const int nW1 = in_sizes[4];          // 2048*64
    const int nE  = in_sizes[3];          // 1,700,000
    const int N   = out_size / LAB;       // 100,000
    const int M   = 2 * N;
    const int nT  = nnz + nE;
    const int K   = (M + (1 << RSH) - 1) >> RSH;   // 391 buckets

    auto align256 = [](size_t x) { return (x + 255) & ~(size_t)255; };
    char* ws = (char*)d_ws;
    size_t off = 0;
    int*   flags   = (int*)(ws + off);   off += 256;
    // front: hF8 (6.4MB) | h2F8 (6.4MB) | zF8 (4MB); Q (int2, 33.6MB) overlays
    // front and dies before gather_feat writes hF8.
    char*  front   = ws + off;
    unsigned* hF8  = (unsigned*)front;                       // N*16 dwords
    unsigned* h2F8 = hF8 + (size_t)N * 16;                   // N*16 dwords
    unsigned char* zb = (unsigned char*)(h2F8 + (size_t)N * 16);  // N*40 B
    size_t frontBytes = (size_t)N * (64 + 64 + 40);
    size_t qBytes     = (size_t)nT * 8;
    off += align256(frontBytes > qBytes ? frontBytes : qBytes);
    int2*  P       = (int2*)(ws + off);  off += align256((size_t)nT * 8);
    int*   rp      = (int*)(ws + off);   off += align256(((size_t)KMAX << RSH) * 4 + 16);
    uint2* w1q     = (uint2*)(ws + off); off += align256((size_t)nW1 * 2);
    int*   cntB    = (int*)(ws + off);   off += KMAX * 4;
    int*   bqstart = (int*)(ws + off);   off += KMAX * 4;
    int*   bq      = (int*)(ws + off);   off += KMAX * 4;
    int2*  Q       = (int2*)front;

    // 1. dtype probe
    probe_kernel<<<1, 64, 0, stream>>>(b1, fidx, flags);

    // 2. zero bucket histogram; stage W1 packed
    zero_kernel<<<1, 256, 0, stream>>>((int4*)cntB, KMAX / 4);
    convw1_kernel<<<(nW1 / 4 + 255) / 256, 256, 0, stream>>>(W1, w1q, flags, nW1 / 4);

    // 3. bucket histogram (LDS-privatized)
    const int HB = 1024;
    histB_kernel<<<HB, 256, 0, stream>>>(fidx, eidx, cntB, flags, nnz, nE, N, HB);

    // 4. bucket scan -> starts + cursors
    scanB_kernel<<<1, KMAX, 0, stream>>>(cntB, bqstart, bq, K);

    // 5. pass A: bucket-grouped scatter into Q
    bucketA_kernel<<<(nT + TILE - 1) / TILE, 256, 0, stream>>>(
        fidx, fval, eidx, ew, flags, bq, Q, nnz, nE, N);

    // 6. pass B: per-bucket row hist/scan in LDS, rp segment, scatter -> P
    bucketB_kernel<<<K, 512, 0, stream>>>(Q, bqstart, rp, P, nT, K);

    // 7. h = sparse_features @ W1 + b1 -> fp8
    int nwaves = (N + 3) / 4;
    int gblocks = (int)(((size_t)nwaves * 64 + 255) / 256);
    gather_feat_kernel<<<gblocks, 256, 0, stream>>>(rp, P, w1q, b1, hF8, flags, N);

    // 8. h2 = relu(A @ h) -> fp8 (gather-only, no epilogue)
    gather_edge_h2_kernel<<<gblocks, 256, 0, stream>>>(rp, P, hF8, h2F8, N);

    // 9. z = h2 @ W2 + b2 -> fp8 (shuffle-free dense)
    int dwaves = (N + 31) / 32;
    int dblocks = (dwaves * 64 + 255) / 256;
    dense_kernel<<<dblocks, 256, 0, stream>>>(h2F8, W2, b2, zb, flags, N);

    // 10. out = log_softmax(A @ z)
    gather_edge_lsm_kernel<<<gblocks, 256, 0, stream>>>(rp, P, (const unsigned*)zb,
                                                        d_out, flags, N);
}

// Round 12
// 362.778 us; speedup vs baseline: 1.1947x; 1.0270x over previous
//
#include <hip/hip_runtime.h>
#include <hip/hip_bf16.h>

// ---------------------------------------------------------------------------
// GCN forward on MI355X — round 12.
// R11 evidence: bucketA top at ~80us, WRITE 100MB vs 33.6MB payload (3x amp),
// VALU 3% -> short bucket runs (~10.5 el = 84B) cause partial-line writebacks.
// Fix: TILE 4096->8192 w/ 512 threads (runs ~21 el = 168B -> amp ~1.4x).
// pr packs (grow<<13)|rank (31 bits). LDS 36KB -> 4 blocks/CU.
// Everything else unchanged from R11.
// ---------------------------------------------------------------------------

#define HID 64
#define LAB 40
#define RSH 9          // 512 rows per bucket
#define KMAX 512       // max buckets (runtime K = 391)
#define TILE_A 8192    // elements per bucketA block (512 threads x 16)

__device__ __forceinline__ float loadF(const void* p, size_t i, int bf16) {
    if (bf16) return __bfloat162float(((const __hip_bfloat16*)p)[i]);
    return ((const float*)p)[i];
}

__device__ __forceinline__ int loadI(const void* p, size_t i, int i64) {
    if (i64) return (int)(((const long long*)p)[i]);
    return ((const int*)p)[i];
}

// packed bf16x2 helpers
__device__ __forceinline__ float bflo(unsigned v) { return __uint_as_float(v << 16); }
__device__ __forceinline__ float bfhi(unsigned v) { return __uint_as_float(v & 0xFFFF0000u); }
__device__ __forceinline__ unsigned bfr16(float x) {
    unsigned u = __float_as_uint(x);
    return (u + 0x7FFFu + ((u >> 16) & 1u)) >> 16;
}
__device__ __forceinline__ unsigned bfpack(float lo, float hi) {
    return bfr16(lo) | (bfr16(hi) << 16);
}

// fp8 e4m3 HW converts
__device__ __forceinline__ unsigned fp8pack4(float a, float b, float c, float d) {
    int r = __builtin_amdgcn_cvt_pk_fp8_f32(a, b, 0, false);
    r = __builtin_amdgcn_cvt_pk_fp8_f32(c, d, r, true);
    return (unsigned)r;
}

// nontemporal int2 load (keep P streams out of L2)
__device__ __forceinline__ void ntload(const int2* P, int idx, int* c, float* w) {
    long long raw = __builtin_nontemporal_load((const long long*)P + idx);
    *c = (int)(unsigned)(raw & 0xFFFFFFFFll);
    *w = __int_as_float((int)(raw >> 32));
}

// dtype probe (validated R1-R11)
__global__ void probe_kernel(const void* b1p, const void* fidxp, int* flags) {
    if (threadIdx.x == 0 && blockIdx.x == 0) {
        const unsigned short* u = (const unsigned short*)b1p;
        int bf16 = 1;
        for (int i = 0; i < 64; i += 2)
            if ((unsigned short)(u[i] & 0x7FFF) >= 0x3E80) { bf16 = 0; break; }
        const int* ip = (const int*)fidxp;
        int i64 = 1;
        for (int i = 1; i < 128; i += 2)
            if (ip[i] != 0) { i64 = 0; break; }
        flags[0] = bf16; flags[1] = i64; flags[2] = 0; flags[3] = 0;
    }
}

__global__ void zero_kernel(int4* p, int n4) {
    int i = blockIdx.x * blockDim.x + threadIdx.x;
    if (i < n4) p[i] = make_int4(0, 0, 0, 0);
}

// W1 -> packed bf16 staging: entry i = features 4i..4i+3 (uint2)
__global__ void convw1_kernel(const void* W1, uint2* w1q, const int* flags, int ne) {
    int i = blockIdx.x * blockDim.x + threadIdx.x;
    if (i < ne) {
        float f0 = loadF(W1, (size_t)4 * i,     flags[0]);
        float f1 = loadF(W1, (size_t)4 * i + 1, flags[0]);
        float f2 = loadF(W1, (size_t)4 * i + 2, flags[0]);
        float f3 = loadF(W1, (size_t)4 * i + 3, flags[0]);
        w1q[i] = make_uint2(bfpack(f0, f1), bfpack(f2, f3));
    }
}

// LDS-privatized bucket histogram (grid-stride)
__global__ void histB_kernel(const void* fidx, const void* eidx, int* cntB,
                             const int* flags, int nnz, int nE, int N, int nb) {
    __shared__ int lh[KMAX];
    for (int t = threadIdx.x; t < KMAX; t += 256) lh[t] = 0;
    __syncthreads();
    const int i64 = flags[1];
    const int nT = nnz + nE;
    for (int i = blockIdx.x * 256 + threadIdx.x; i < nT; i += nb * 256) {
        int grow = (i < nnz) ? loadI(fidx, (size_t)i, i64)
                             : N + loadI(eidx, (size_t)(i - nnz), i64);
        atomicAdd(&lh[grow >> RSH], 1);
    }
    __syncthreads();
    for (int t = threadIdx.x; t < KMAX; t += 256) {
        int c = lh[t];
        if (c) atomicAdd(&cntB[t], c);
    }
}

// single-block exclusive scan of bucket counts -> bqstart + bq cursors
__global__ void scanB_kernel(const int* cntB, int* bqstart, int* bq, int K) {
    __shared__ int s[KMAX];
    int t = threadIdx.x;
    int x = (t < K) ? cntB[t] : 0;
    s[t] = x;
    __syncthreads();
    for (int off = 1; off < KMAX; off <<= 1) {
        int v = (t >= off) ? s[t - off] : 0;
        __syncthreads();
        s[t] += v;
        __syncthreads();
    }
    if (t < K) { int st = s[t] - x; bqstart[t] = st; bq[t] = st; }
}

// Pass A: bucket-grouped scatter into Q. 512 threads, TILE_A=8192.
// pr packs (grow<<13)|rank (grow<2^18, rank<2^13).
__global__ void bucketA_kernel(const void* fidx, const void* fval,
                               const void* eidx, const void* ew,
                               const int* flags, int* bq, int2* Q,
                               int nnz, int nE, int N) {
    __shared__ int hist[KMAX];
    __shared__ int gbase[KMAX];
    __shared__ int pr[TILE_A];
    const int i64 = flags[1], bf16 = flags[0];
    const int nT = nnz + nE;
    const int base = blockIdx.x * TILE_A;
    if (threadIdx.x < KMAX) hist[threadIdx.x] = 0;
    __syncthreads();
#pragma unroll
    for (int k = 0; k < TILE_A / 512; k++) {
        int i = base + k * 512 + threadIdx.x;
        if (i < nT) {
            int grow = (i < nnz) ? loadI(fidx, (size_t)i, i64)
                                 : N + loadI(eidx, (size_t)(i - nnz), i64);
            int rank = atomicAdd(&hist[grow >> RSH], 1);
            pr[k * 512 + threadIdx.x] = (grow << 13) | rank;
        }
    }
    __syncthreads();
    if (threadIdx.x < KMAX) {
        int c = hist[threadIdx.x];
        gbase[threadIdx.x] = c ? atomicAdd(&bq[threadIdx.x], c) : 0;
    }
    __syncthreads();
#pragma unroll
    for (int k = 0; k < TILE_A / 512; k++) {
        int i = base + k * 512 + threadIdx.x;
        if (i < nT) {
            int c; float v;
            if (i < nnz) {
                c = loadI(fidx, (size_t)nnz + i, i64);
                v = loadF(fval, (size_t)i, bf16);
            } else {
                int j = i - nnz;
                c = loadI(eidx, (size_t)nE + j, i64);
                v = loadF(ew, (size_t)j, bf16);
            }
            int p = pr[k * 512 + threadIdx.x];
            int grow = p >> 13;
            int pos = gbase[grow >> RSH] + (p & 0x1FFF);
            Q[pos] = make_int2(((grow & ((1 << RSH) - 1)) << 17) | c,
                               __float_as_int(v));
        }
    }
}

// Pass B: one 512-thread block per bucket; LDS row hist + scan -> rp segment,
// scatter to P with LDS rank cursors.
__global__ void bucketB_kernel(const int2* Q, const int* bqstart, int* rp,
                               int2* P, int nT, int K) {
    __shared__ int lh[1 << RSH];
    __shared__ int s[1 << RSH];
    __shared__ int lstart[1 << RSH];
    const int b = blockIdx.x;
    const int t = threadIdx.x;
    const int start = bqstart[b];
    const int end = (b == K - 1) ? nT : bqstart[b + 1];
    lh[t] = 0;
    __syncthreads();
    for (int i = start + t; i < end; i += 512)
        atomicAdd(&lh[((unsigned)Q[i].x) >> 17], 1);
    __syncthreads();
    int x = lh[t];
    s[t] = x;
    __syncthreads();
    for (int off = 1; off < (1 << RSH); off <<= 1) {
        int v = (t >= off) ? s[t - off] : 0;
        __syncthreads();
        s[t] += v;
        __syncthreads();
    }
    int rowstart = start + s[t] - x;
    rp[(b << RSH) + t] = rowstart;
    lstart[t] = rowstart;
    lh[t] = 0;
    __syncthreads();
    for (int i = start + t; i < end; i += 512) {
        int2 el = Q[i];
        int lr = ((unsigned)el.x) >> 17;
        int rank = atomicAdd(&lh[lr], 1);
        P[lstart[lr] + rank] = make_int2(el.x & 0x1FFFF, el.y);
    }
}

// 4 rows/wave feat gather: h = b1 + sum v*W1[c], stored fp8 (row*16+gl dword).
__global__ void gather_feat_kernel(const int* rp, const int2* P,
                                   const uint2* w1q, const void* b1,
                                   unsigned* hF8, const int* flags, int N) {
    int bf16 = flags[0];
    int wave = (blockIdx.x * blockDim.x + threadIdx.x) >> 6;
    int lane = threadIdx.x & 63;
    int g = lane >> 4, gl = lane & 15;
    int row = 4 * wave + g;
    int s = 0, e = 0;
    if (row < N) { s = rp[row]; e = rp[row + 1]; }
    float a0 = loadF(b1, (size_t)4 * gl,     bf16);
    float a1 = loadF(b1, (size_t)4 * gl + 1, bf16);
    float a2 = loadF(b1, (size_t)4 * gl + 2, bf16);
    float a3 = loadF(b1, (size_t)4 * gl + 3, bf16);
    const int sb = g << 4;
    for (int base = s; base < e; base += 16) {
        int idx = base + gl;
        int cl = 0; float vl = 0.f;
        if (idx < e) ntload(P, idx, &cl, &vl);
        int cnt = min(16, e - base);
        int j = 0;
        for (; j + 4 <= cnt; j += 4) {
            int   c0 = __shfl(cl, sb + j),     c1 = __shfl(cl, sb + j + 1);
            int   c2 = __shfl(cl, sb + j + 2), c3 = __shfl(cl, sb + j + 3);
            float v0 = __shfl(vl, sb + j),     v1 = __shfl(vl, sb + j + 1);
            float v2 = __shfl(vl, sb + j + 2), v3 = __shfl(vl, sb + j + 3);
            uint2 u0 = w1q[c0 * 16 + gl];
            uint2 u1 = w1q[c1 * 16 + gl];
            uint2 u2 = w1q[c2 * 16 + gl];
            uint2 u3 = w1q[c3 * 16 + gl];
            a0 += v0 * bflo(u0.x); a1 += v0 * bfhi(u0.x);
            a2 += v0 * bflo(u0.y); a3 += v0 * bfhi(u0.y);
            a0 += v1 * bflo(u1.x); a1 += v1 * bfhi(u1.x);
            a2 += v1 * bflo(u1.y); a3 += v1 * bfhi(u1.y);
            a0 += v2 * bflo(u2.x); a1 += v2 * bfhi(u2.x);
            a2 += v2 * bflo(u2.y); a3 += v2 * bfhi(u2.y);
            a0 += v3 * bflo(u3.x); a1 += v3 * bfhi(u3.x);
            a2 += v3 * bflo(u3.y); a3 += v3 * bfhi(u3.y);
        }
        for (; j < cnt; j++) {
            int   c = __shfl(cl, sb + j);
            float v = __shfl(vl, sb + j);
            uint2 u = w1q[c * 16 + gl];
            a0 += v * bflo(u.x); a1 += v * bfhi(u.x);
            a2 += v * bflo(u.y); a3 += v * bfhi(u.y);
        }
    }
    if (row < N) hF8[row * 16 + gl] = fp8pack4(a0, a1, a2, a3);
}

// Merged propagation, NO epilogue: h2 = relu(A @ h), fp8 in / fp8 out.
__global__ void gather_edge_h2_kernel(const int* rp, const int2* P,
                                      const unsigned* hF8, unsigned* h2F8,
                                      int N) {
    int wave = (blockIdx.x * blockDim.x + threadIdx.x) >> 6;
    int lane = threadIdx.x & 63;
    int g = lane >> 4, gl = lane & 15;
    int row = 4 * wave + g;
    int s = 0, e = 0;
    if (row < N) { s = rp[N + row]; e = rp[N + row + 1]; }
    float a0 = 0.f, a1 = 0.f, a2 = 0.f, a3 = 0.f;
    const int sb = g << 4;
    for (int base = s; base < e; base += 16) {
        int idx = base + gl;
        int cl = 0; float wl = 0.f;
        if (idx < e) ntload(P, idx, &cl, &wl);
        int cnt = min(16, e - base);
        int j = 0;
        for (; j + 8 <= cnt; j += 8) {
            int   c0 = __shfl(cl, sb + j),     c1 = __shfl(cl, sb + j + 1);
            int   c2 = __shfl(cl, sb + j + 2), c3 = __shfl(cl, sb + j + 3);
            int   c4 = __shfl(cl, sb + j + 4), c5 = __shfl(cl, sb + j + 5);
            int   c6 = __shfl(cl, sb + j + 6), c7 = __shfl(cl, sb + j + 7);
            float w0 = __shfl(wl, sb + j),     w1 = __shfl(wl, sb + j + 1);
            float w2 = __shfl(wl, sb + j + 2), w3 = __shfl(wl, sb + j + 3);
            float w4 = __shfl(wl, sb + j + 4), w5 = __shfl(wl, sb + j + 5);
            float w6 = __shfl(wl, sb + j + 6), w7 = __shfl(wl, sb + j + 7);
            int u0 = (int)hF8[c0 * 16 + gl];
            int u1 = (int)hF8[c1 * 16 + gl];
            int u2 = (int)hF8[c2 * 16 + gl];
            int u3 = (int)hF8[c3 * 16 + gl];
            int u4 = (int)hF8[c4 * 16 + gl];
            int u5 = (int)hF8[c5 * 16 + gl];
            int u6 = (int)hF8[c6 * 16 + gl];
            int u7 = (int)hF8[c7 * 16 + gl];
            a0 += w0 * __builtin_amdgcn_cvt_f32_fp8(u0, 0);
            a1 += w0 * __builtin_amdgcn_cvt_f32_fp8(u0, 1);
            a2 += w0 * __builtin_amdgcn_cvt_f32_fp8(u0, 2);
            a3 += w0 * __builtin_amdgcn_cvt_f32_fp8(u0, 3);
            a0 += w1 * __builtin_amdgcn_cvt_f32_fp8(u1, 0);
            a1 += w1 * __builtin_amdgcn_cvt_f32_fp8(u1, 1);
            a2 += w1 * __builtin_amdgcn_cvt_f32_fp8(u1, 2);
            a3 += w1 * __builtin_amdgcn_cvt_f32_fp8(u1, 3);
            a0 += w2 * __builtin_amdgcn_cvt_f32_fp8(u2, 0);
            a1 += w2 * __builtin_amdgcn_cvt_f32_fp8(u2, 1);
            a2 += w2 * __builtin_amdgcn_cvt_f32_fp8(u2, 2);
            a3 += w2 * __builtin_amdgcn_cvt_f32_fp8(u2, 3);
            a0 += w3 * __builtin_amdgcn_cvt_f32_fp8(u3, 0);
            a1 += w3 * __builtin_amdgcn_cvt_f32_fp8(u3, 1);
            a2 += w3 * __builtin_amdgcn_cvt_f32_fp8(u3, 2);
            a3 += w3 * __builtin_amdgcn_cvt_f32_fp8(u3, 3);
            a0 += w4 * __builtin_amdgcn_cvt_f32_fp8(u4, 0);
            a1 += w4 * __builtin_amdgcn_cvt_f32_fp8(u4, 1);
            a2 += w4 * __builtin_amdgcn_cvt_f32_fp8(u4, 2);
            a3 += w4 * __builtin_amdgcn_cvt_f32_fp8(u4, 3);
            a0 += w5 * __builtin_amdgcn_cvt_f32_fp8(u5, 0);
            a1 += w5 * __builtin_amdgcn_cvt_f32_fp8(u5, 1);
            a2 += w5 * __builtin_amdgcn_cvt_f32_fp8(u5, 2);
            a3 += w5 * __builtin_amdgcn_cvt_f32_fp8(u5, 3);
            a0 += w6 * __builtin_amdgcn_cvt_f32_fp8(u6, 0);
            a1 += w6 * __builtin_amdgcn_cvt_f32_fp8(u6, 1);
            a2 += w6 * __builtin_amdgcn_cvt_f32_fp8(u6, 2);
            a3 += w6 * __builtin_amdgcn_cvt_f32_fp8(u6, 3);
            a0 += w7 * __builtin_amdgcn_cvt_f32_fp8(u7, 0);
            a1 += w7 * __builtin_amdgcn_cvt_f32_fp8(u7, 1);
            a2 += w7 * __builtin_amdgcn_cvt_f32_fp8(u7, 2);
            a3 += w7 * __builtin_amdgcn_cvt_f32_fp8(u7, 3);
        }
        for (; j < cnt; j++) {
            int   c = __shfl(cl, sb + j);
            float w = __shfl(wl, sb + j);
            int u = (int)hF8[c * 16 + gl];
            a0 += w * __builtin_amdgcn_cvt_f32_fp8(u, 0);
            a1 += w * __builtin_amdgcn_cvt_f32_fp8(u, 1);
            a2 += w * __builtin_amdgcn_cvt_f32_fp8(u, 2);
            a3 += w * __builtin_amdgcn_cvt_f32_fp8(u, 3);
        }
    }
    if (row < N)
        h2F8[row * 16 + gl] = fp8pack4(fmaxf(a0, 0.f), fmaxf(a1, 0.f),
                                       fmaxf(a2, 0.f), fmaxf(a3, 0.f));
}

// Shuffle-free, LDS-free dense: z = relu_h2 @ W2 + b2, fp8 out.
__global__ void dense_kernel(const unsigned* h2F8, const void* W2, const void* b2,
                             unsigned char* zb, const int* flags, int N) {
    int bf16 = flags[0];
    int wave = (int)((blockIdx.x * blockDim.x + threadIdx.x) >> 6);
    int lane = threadIdx.x & 63;
    int jj = (lane < LAB) ? lane : 0;
    float w2c[HID];
#pragma unroll
    for (int k = 0; k < HID; k++) w2c[k] = loadF(W2, (size_t)k * LAB + jj, bf16);
    float bias = loadF(b2, (size_t)jj, bf16);
    int r0 = wave * 32;
    int r1 = min(r0 + 32, N);
    for (int r = r0; r < r1; r++) {
        const unsigned* hr = h2F8 + (size_t)r * 16;
        float acc = bias;
#pragma unroll
        for (int k16 = 0; k16 < 16; k16++) {
            int d = (int)hr[k16];
            acc += __builtin_amdgcn_cvt_f32_fp8(d, 0) * w2c[4 * k16];
            acc += __builtin_amdgcn_cvt_f32_fp8(d, 1) * w2c[4 * k16 + 1];
            acc += __builtin_amdgcn_cvt_f32_fp8(d, 2) * w2c[4 * k16 + 2];
            acc += __builtin_amdgcn_cvt_f32_fp8(d, 3) * w2c[4 * k16 + 3];
        }
        if (lane < LAB) {
            int pk = __builtin_amdgcn_cvt_pk_fp8_f32(acc, acc, 0, false);
            zb[(size_t)r * LAB + lane] = (unsigned char)(pk & 0xFF);
        }
    }
}

// 4 rows/wave: z2 = A@z (fp8 gather), fused log_softmax -> out.
__global__ void gather_edge_lsm_kernel(const int* rp, const int2* P,
                                       const unsigned* zF8, void* out,
                                       const int* flags, int N) {
    int bf16 = flags[0];
    int wave = (blockIdx.x * blockDim.x + threadIdx.x) >> 6;
    int lane = threadIdx.x & 63;
    int g = lane >> 4, gl = lane & 15;
    int row = 4 * wave + g;
    int s = 0, e = 0;
    if (row < N) { s = rp[N + row]; e = rp[N + row + 1]; }
    float a0 = 0.f, a1 = 0.f, a2 = 0.f, a3 = 0.f;
    const int sb = g << 4;
    const int act = (gl < 10);
    for (int base = s; base < e; base += 16) {
        int idx = base + gl;
        int cl = 0; float wl = 0.f;
        if (idx < e) ntload(P, idx, &cl, &wl);
        int cnt = min(16, e - base);
        int j = 0;
        for (; j + 4 <= cnt; j += 4) {
            int   c0 = __shfl(cl, sb + j),     c1 = __shfl(cl, sb + j + 1);
            int   c2 = __shfl(cl, sb + j + 2), c3 = __shfl(cl, sb + j + 3);
            float w0 = __shfl(wl, sb + j),     w1 = __shfl(wl, sb + j + 1);
            float w2 = __shfl(wl, sb + j + 2), w3 = __shfl(wl, sb + j + 3);
            if (act) {
                int u0 = (int)zF8[c0 * 10 + gl];
                int u1 = (int)zF8[c1 * 10 + gl];
                int u2 = (int)zF8[c2 * 10 + gl];
                int u3 = (int)zF8[c3 * 10 + gl];
                a0 += w0 * __builtin_amdgcn_cvt_f32_fp8(u0, 0);
                a1 += w0 * __builtin_amdgcn_cvt_f32_fp8(u0, 1);
                a2 += w0 * __builtin_amdgcn_cvt_f32_fp8(u0, 2);
                a3 += w0 * __builtin_amdgcn_cvt_f32_fp8(u0, 3);
                a0 += w1 * __builtin_amdgcn_cvt_f32_fp8(u1, 0);
                a1 += w1 * __builtin_amdgcn_cvt_f32_fp8(u1, 1);
                a2 += w1 * __builtin_amdgcn_cvt_f32_fp8(u1, 2);
                a3 += w1 * __builtin_amdgcn_cvt_f32_fp8(u1, 3);
                a0 += w2 * __builtin_amdgcn_cvt_f32_fp8(u2, 0);
                a1 += w2 * __builtin_amdgcn_cvt_f32_fp8(u2, 1);
                a2 += w2 * __builtin_amdgcn_cvt_f32_fp8(u2, 2);
                a3 += w2 * __builtin_amdgcn_cvt_f32_fp8(u2, 3);
                a0 += w3 * __builtin_amdgcn_cvt_f32_fp8(u3, 0);
                a1 += w3 * __builtin_amdgcn_cvt_f32_fp8(u3, 1);
                a2 += w3 * __builtin_amdgcn_cvt_f32_fp8(u3, 2);
                a3 += w3 * __builtin_amdgcn_cvt_f32_fp8(u3, 3);
            }
        }
        for (; j < cnt; j++) {
            int   c = __shfl(cl, sb + j);
            float w = __shfl(wl, sb + j);
            if (act) {
                int u = (int)zF8[c * 10 + gl];
                a0 += w * __builtin_amdgcn_cvt_f32_fp8(u, 0);
                a1 += w * __builtin_amdgcn_cvt_f32_fp8(u, 1);
                a2 += w * __builtin_amdgcn_cvt_f32_fp8(u, 2);
                a3 += w * __builtin_amdgcn_cvt_f32_fp8(u, 3);
            }
        }
    }
    float m = act ? fmaxf(fmaxf(a0, a1), fmaxf(a2, a3)) : -INFINITY;
#pragma unroll
    for (int off = 8; off; off >>= 1) m = fmaxf(m, __shfl_xor(m, off));
    float es = act ? (__expf(a0 - m) + __expf(a1 - m) + __expf(a2 - m) + __expf(a3 - m)) : 0.f;
#pragma unroll
    for (int off = 8; off; off >>= 1) es += __shfl_xor(es, off);
    float lse = m + __logf(es);
    if (act && row < N) {
        float o0 = a0 - lse, o1 = a1 - lse, o2 = a2 - lse, o3 = a3 - lse;
        if (bf16) {
            ((uint2*)out)[(size_t)row * 10 + gl] =
                make_uint2(bfpack(o0, o1), bfpack(o2, o3));
        } else {
            float4 v = make_float4(o0, o1, o2, o3);
            ((float4*)out)[(size_t)row * 10 + gl] = v;
        }
    }
}

extern "C" void kernel_launch(void* const* d_in, const int* in_sizes, int n_in,
                              void* d_out, int out_size, void* d_ws, size_t ws_size,
                              hipStream_t stream) {
    const void* fidx = d_in[0];
    const void* fval = d_in[1];
    const void* eidx = d_in[2];
    const void* ew   = d_in[3];
    const void* W1   = d_in[4];
    const void* b1   = d_in[5];
    const void* W2   = d_in[6];
    const void* b2   = d_in[7];

    const int nnz = in_sizes[1];          // 2,500,000
    const int nW1 = in_sizes[4];          // 2048*64
    const int nE  = in_sizes[3];          // 1,700,000
    const int N   = out_size / LAB;       // 100,000
    const int M   = 2 * N;
    const int nT  = nnz + nE;
    const int K   = (M + (1 << RSH) - 1) >> RSH;   // 391 buckets

    auto align256 = [](size_t x) { return (x + 255) & ~(size_t)255; };
    char* ws = (char*)d_ws;
    size_t off = 0;
    int*   flags   = (int*)(ws + off);   off += 256;
    // front: hF8 (6.4MB) | h2F8 (6.4MB) | zF8 (4MB); Q (int2, 33.6MB) overlays
    // front and dies before gather_feat writes hF8.
    char*  front   = ws + off;
    unsigned* hF8  = (unsigned*)front;                       // N*16 dwords
    unsigned* h2F8 = hF8 + (size_t)N * 16;                   // N*16 dwords
    unsigned char* zb = (unsigned char*)(h2F8 + (size_t)N * 16);  // N*40 B
    size_t frontBytes = (size_t)N * (64 + 64 + 40);
    size_t qBytes     = (size_t)nT * 8;
    off += align256(frontBytes > qBytes ? frontBytes : qBytes);
    int2*  P       = (int2*)(ws + off);  off += align256((size_t)nT * 8);
    int*   rp      = (int*)(ws + off);   off += align256(((size_t)KMAX << RSH) * 4 + 16);
    uint2* w1q     = (uint2*)(ws + off); off += align256((size_t)nW1 * 2);
    int*   cntB    = (int*)(ws + off);   off += KMAX * 4;
    int*   bqstart = (int*)(ws + off);   off += KMAX * 4;
    int*   bq      = (int*)(ws + off);   off += KMAX * 4;
    int2*  Q       = (int2*)front;

    // 1. dtype probe
    probe_kernel<<<1, 64, 0, stream>>>(b1, fidx, flags);

    // 2. zero bucket histogram; stage W1 packed
    zero_kernel<<<1, 256, 0, stream>>>((int4*)cntB, KMAX / 4);
    convw1_kernel<<<(nW1 / 4 + 255) / 256, 256, 0, stream>>>(W1, w1q, flags, nW1 / 4);

    // 3. bucket histogram (LDS-privatized)
    const int HB = 1024;
    histB_kernel<<<HB, 256, 0, stream>>>(fidx, eidx, cntB, flags, nnz, nE, N, HB);

    // 4. bucket scan -> starts + cursors
    scanB_kernel<<<1, KMAX, 0, stream>>>(cntB, bqstart, bq, K);

    // 5. pass A: bucket-grouped scatter into Q (8192-elem tiles, 512 thr)
    bucketA_kernel<<<(nT + TILE_A - 1) / TILE_A, 512, 0, stream>>>(
        fidx, fval, eidx, ew, flags, bq, Q, nnz, nE, N);

    // 6. pass B: per-bucket row hist/scan in LDS, rp segment, scatter -> P
    bucketB_kernel<<<K, 512, 0, stream>>>(Q, bqstart, rp, P, nT, K);

    // 7. h = sparse_features @ W1 + b1 -> fp8
    int nwaves = (N + 3) / 4;
    int gblocks = (int)(((size_t)nwaves * 64 + 255) / 256);
    gather_feat_kernel<<<gblocks, 256, 0, stream>>>(rp, P, w1q, b1, hF8, flags, N);

    // 8. h2 = relu(A @ h) -> fp8 (gather-only, no epilogue)
    gather_edge_h2_kernel<<<gblocks, 256, 0, stream>>>(rp, P, hF8, h2F8, N);

    // 9. z = h2 @ W2 + b2 -> fp8 (shuffle-free dense)
    int dwaves = (N + 31) / 32;
    int dblocks = (dwaves * 64 + 255) / 256;
    dense_kernel<<<dblocks, 256, 0, stream>>>(h2F8, W2, b2, zb, flags, N);

    // 10. out = log_softmax(A @ z)
    gather_edge_lsm_kernel<<<gblocks, 256, 0, stream>>>(rp, P, (const unsigned*)zb,
                                                        d_out, flags, N);
}

// Round 13
// 357.125 us; speedup vs baseline: 1.2136x; 1.0158x over previous
//
#include <hip/hip_runtime.h>
#include <hip/hip_bf16.h>

// ---------------------------------------------------------------------------
// GCN forward on MI355X — round 13.
// R12 evidence: bucketA still top (~60us), WRITE 53MB vs 33.6 ideal, VALU 3.8%
// -> still write-amp-bound; tile capped by pr[TILE] LDS (32KB). Fix: drop pr
// entirely — recompute rank in phase 3 via a second LDS histogram pass (ranks
// only need per-block-per-bucket uniqueness). LDS 4KB -> TILE_A 16384
// (runs ~42 el = 336B, amp ~1.2x). Phase 3 re-reads row idx (L3-cached).
// Everything else unchanged from R12.
// ---------------------------------------------------------------------------

#define HID 64
#define LAB 40
#define RSH 9          // 512 rows per bucket
#define KMAX 512       // max buckets (runtime K = 391)
#define TILE_A 16384   // elements per bucketA block (512 threads x 32)

__device__ __forceinline__ float loadF(const void* p, size_t i, int bf16) {
    if (bf16) return __bfloat162float(((const __hip_bfloat16*)p)[i]);
    return ((const float*)p)[i];
}

__device__ __forceinline__ int loadI(const void* p, size_t i, int i64) {
    if (i64) return (int)(((const long long*)p)[i]);
    return ((const int*)p)[i];
}

// packed bf16x2 helpers
__device__ __forceinline__ float bflo(unsigned v) { return __uint_as_float(v << 16); }
__device__ __forceinline__ float bfhi(unsigned v) { return __uint_as_float(v & 0xFFFF0000u); }
__device__ __forceinline__ unsigned bfr16(float x) {
    unsigned u = __float_as_uint(x);
    return (u + 0x7FFFu + ((u >> 16) & 1u)) >> 16;
}
__device__ __forceinline__ unsigned bfpack(float lo, float hi) {
    return bfr16(lo) | (bfr16(hi) << 16);
}

// fp8 e4m3 HW converts
__device__ __forceinline__ unsigned fp8pack4(float a, float b, float c, float d) {
    int r = __builtin_amdgcn_cvt_pk_fp8_f32(a, b, 0, false);
    r = __builtin_amdgcn_cvt_pk_fp8_f32(c, d, r, true);
    return (unsigned)r;
}

// nontemporal int2 load (keep P streams out of L2)
__device__ __forceinline__ void ntload(const int2* P, int idx, int* c, float* w) {
    long long raw = __builtin_nontemporal_load((const long long*)P + idx);
    *c = (int)(unsigned)(raw & 0xFFFFFFFFll);
    *w = __int_as_float((int)(raw >> 32));
}

// dtype probe (validated R1-R12)
__global__ void probe_kernel(const void* b1p, const void* fidxp, int* flags) {
    if (threadIdx.x == 0 && blockIdx.x == 0) {
        const unsigned short* u = (const unsigned short*)b1p;
        int bf16 = 1;
        for (int i = 0; i < 64; i += 2)
            if ((unsigned short)(u[i] & 0x7FFF) >= 0x3E80) { bf16 = 0; break; }
        const int* ip = (const int*)fidxp;
        int i64 = 1;
        for (int i = 1; i < 128; i += 2)
            if (ip[i] != 0) { i64 = 0; break; }
        flags[0] = bf16; flags[1] = i64; flags[2] = 0; flags[3] = 0;
    }
}

__global__ void zero_kernel(int4* p, int n4) {
    int i = blockIdx.x * blockDim.x + threadIdx.x;
    if (i < n4) p[i] = make_int4(0, 0, 0, 0);
}

// W1 -> packed bf16 staging: entry i = features 4i..4i+3 (uint2)
__global__ void convw1_kernel(const void* W1, uint2* w1q, const int* flags, int ne) {
    int i = blockIdx.x * blockDim.x + threadIdx.x;
    if (i < ne) {
        float f0 = loadF(W1, (size_t)4 * i,     flags[0]);
        float f1 = loadF(W1, (size_t)4 * i + 1, flags[0]);
        float f2 = loadF(W1, (size_t)4 * i + 2, flags[0]);
        float f3 = loadF(W1, (size_t)4 * i + 3, flags[0]);
        w1q[i] = make_uint2(bfpack(f0, f1), bfpack(f2, f3));
    }
}

// LDS-privatized bucket histogram (grid-stride)
__global__ void histB_kernel(const void* fidx, const void* eidx, int* cntB,
                             const int* flags, int nnz, int nE, int N, int nb) {
    __shared__ int lh[KMAX];
    for (int t = threadIdx.x; t < KMAX; t += 256) lh[t] = 0;
    __syncthreads();
    const int i64 = flags[1];
    const int nT = nnz + nE;
    for (int i = blockIdx.x * 256 + threadIdx.x; i < nT; i += nb * 256) {
        int grow = (i < nnz) ? loadI(fidx, (size_t)i, i64)
                             : N + loadI(eidx, (size_t)(i - nnz), i64);
        atomicAdd(&lh[grow >> RSH], 1);
    }
    __syncthreads();
    for (int t = threadIdx.x; t < KMAX; t += 256) {
        int c = lh[t];
        if (c) atomicAdd(&cntB[t], c);
    }
}

// single-block exclusive scan of bucket counts -> bqstart + bq cursors
__global__ void scanB_kernel(const int* cntB, int* bqstart, int* bq, int K) {
    __shared__ int s[KMAX];
    int t = threadIdx.x;
    int x = (t < K) ? cntB[t] : 0;
    s[t] = x;
    __syncthreads();
    for (int off = 1; off < KMAX; off <<= 1) {
        int v = (t >= off) ? s[t - off] : 0;
        __syncthreads();
        s[t] += v;
        __syncthreads();
    }
    if (t < K) { int st = s[t] - x; bqstart[t] = st; bq[t] = st; }
}

// Pass A: bucket-grouped scatter into Q. 512 threads, TILE_A=16384, rank-free
// (phase 3 recomputes rank via second LDS histogram pass).
__global__ void bucketA_kernel(const void* fidx, const void* fval,
                               const void* eidx, const void* ew,
                               const int* flags, int* bq, int2* Q,
                               int nnz, int nE, int N) {
    __shared__ int hist[KMAX];
    __shared__ int gbase[KMAX];
    const int i64 = flags[1], bf16 = flags[0];
    const int nT = nnz + nE;
    const int base = blockIdx.x * TILE_A;
    if (threadIdx.x < KMAX) hist[threadIdx.x] = 0;
    __syncthreads();
    // phase 1: block-local bucket histogram
#pragma unroll 4
    for (int k = 0; k < TILE_A / 512; k++) {
        int i = base + k * 512 + threadIdx.x;
        if (i < nT) {
            int grow = (i < nnz) ? loadI(fidx, (size_t)i, i64)
                                 : N + loadI(eidx, (size_t)(i - nnz), i64);
            atomicAdd(&hist[grow >> RSH], 1);
        }
    }
    __syncthreads();
    // phase 2: reserve per-bucket runs; reset hist as rank cursors
    if (threadIdx.x < KMAX) {
        int c = hist[threadIdx.x];
        gbase[threadIdx.x] = c ? atomicAdd(&bq[threadIdx.x], c) : 0;
        hist[threadIdx.x] = 0;
    }
    __syncthreads();
    // phase 3: re-read row+col+val, recompute rank, bucket-grouped write
#pragma unroll 4
    for (int k = 0; k < TILE_A / 512; k++) {
        int i = base + k * 512 + threadIdx.x;
        if (i < nT) {
            int grow, c; float v;
            if (i < nnz) {
                grow = loadI(fidx, (size_t)i, i64);
                c    = loadI(fidx, (size_t)nnz + i, i64);
                v    = loadF(fval, (size_t)i, bf16);
            } else {
                int j = i - nnz;
                grow = N + loadI(eidx, (size_t)j, i64);
                c    = loadI(eidx, (size_t)nE + j, i64);
                v    = loadF(ew, (size_t)j, bf16);
            }
            int b = grow >> RSH;
            int rank = atomicAdd(&hist[b], 1);
            Q[gbase[b] + rank] = make_int2(((grow & ((1 << RSH) - 1)) << 17) | c,
                                           __float_as_int(v));
        }
    }
}

// Pass B: one 512-thread block per bucket; LDS row hist + scan -> rp segment,
// scatter to P with LDS rank cursors.
__global__ void bucketB_kernel(const int2* Q, const int* bqstart, int* rp,
                               int2* P, int nT, int K) {
    __shared__ int lh[1 << RSH];
    __shared__ int s[1 << RSH];
    __shared__ int lstart[1 << RSH];
    const int b = blockIdx.x;
    const int t = threadIdx.x;
    const int start = bqstart[b];
    const int end = (b == K - 1) ? nT : bqstart[b + 1];
    lh[t] = 0;
    __syncthreads();
    for (int i = start + t; i < end; i += 512)
        atomicAdd(&lh[((unsigned)Q[i].x) >> 17], 1);
    __syncthreads();
    int x = lh[t];
    s[t] = x;
    __syncthreads();
    for (int off = 1; off < (1 << RSH); off <<= 1) {
        int v = (t >= off) ? s[t - off] : 0;
        __syncthreads();
        s[t] += v;
        __syncthreads();
    }
    int rowstart = start + s[t] - x;
    rp[(b << RSH) + t] = rowstart;
    lstart[t] = rowstart;
    lh[t] = 0;
    __syncthreads();
    for (int i = start + t; i < end; i += 512) {
        int2 el = Q[i];
        int lr = ((unsigned)el.x) >> 17;
        int rank = atomicAdd(&lh[lr], 1);
        P[lstart[lr] + rank] = make_int2(el.x & 0x1FFFF, el.y);
    }
}

// 4 rows/wave feat gather: h = b1 + sum v*W1[c], stored fp8 (row*16+gl dword).
__global__ void gather_feat_kernel(const int* rp, const int2* P,
                                   const uint2* w1q, const void* b1,
                                   unsigned* hF8, const int* flags, int N) {
    int bf16 = flags[0];
    int wave = (blockIdx.x * blockDim.x + threadIdx.x) >> 6;
    int lane = threadIdx.x & 63;
    int g = lane >> 4, gl = lane & 15;
    int row = 4 * wave + g;
    int s = 0, e = 0;
    if (row < N) { s = rp[row]; e = rp[row + 1]; }
    float a0 = loadF(b1, (size_t)4 * gl,     bf16);
    float a1 = loadF(b1, (size_t)4 * gl + 1, bf16);
    float a2 = loadF(b1, (size_t)4 * gl + 2, bf16);
    float a3 = loadF(b1, (size_t)4 * gl + 3, bf16);
    const int sb = g << 4;
    for (int base = s; base < e; base += 16) {
        int idx = base + gl;
        int cl = 0; float vl = 0.f;
        if (idx < e) ntload(P, idx, &cl, &vl);
        int cnt = min(16, e - base);
        int j = 0;
        for (; j + 4 <= cnt; j += 4) {
            int   c0 = __shfl(cl, sb + j),     c1 = __shfl(cl, sb + j + 1);
            int   c2 = __shfl(cl, sb + j + 2), c3 = __shfl(cl, sb + j + 3);
            float v0 = __shfl(vl, sb + j),     v1 = __shfl(vl, sb + j + 1);
            float v2 = __shfl(vl, sb + j + 2), v3 = __shfl(vl, sb + j + 3);
            uint2 u0 = w1q[c0 * 16 + gl];
            uint2 u1 = w1q[c1 * 16 + gl];
            uint2 u2 = w1q[c2 * 16 + gl];
            uint2 u3 = w1q[c3 * 16 + gl];
            a0 += v0 * bflo(u0.x); a1 += v0 * bfhi(u0.x);
            a2 += v0 * bflo(u0.y); a3 += v0 * bfhi(u0.y);
            a0 += v1 * bflo(u1.x); a1 += v1 * bfhi(u1.x);
            a2 += v1 * bflo(u1.y); a3 += v1 * bfhi(u1.y);
            a0 += v2 * bflo(u2.x); a1 += v2 * bfhi(u2.x);
            a2 += v2 * bflo(u2.y); a3 += v2 * bfhi(u2.y);
            a0 += v3 * bflo(u3.x); a1 += v3 * bfhi(u3.x);
            a2 += v3 * bflo(u3.y); a3 += v3 * bfhi(u3.y);
        }
        for (; j < cnt; j++) {
            int   c = __shfl(cl, sb + j);
            float v = __shfl(vl, sb + j);
            uint2 u = w1q[c * 16 + gl];
            a0 += v * bflo(u.x); a1 += v * bfhi(u.x);
            a2 += v * bflo(u.y); a3 += v * bfhi(u.y);
        }
    }
    if (row < N) hF8[row * 16 + gl] = fp8pack4(a0, a1, a2, a3);
}

// Merged propagation, NO epilogue: h2 = relu(A @ h), fp8 in / fp8 out.
__global__ void gather_edge_h2_kernel(const int* rp, const int2* P,
                                      const unsigned* hF8, unsigned* h2F8,
                                      int N) {
    int wave = (blockIdx.x * blockDim.x + threadIdx.x) >> 6;
    int lane = threadIdx.x & 63;
    int g = lane >> 4, gl = lane & 15;
    int row = 4 * wave + g;
    int s = 0, e = 0;
    if (row < N) { s = rp[N + row]; e = rp[N + row + 1]; }
    float a0 = 0.f, a1 = 0.f, a2 = 0.f, a3 = 0.f;
    const int sb = g << 4;
    for (int base = s; base < e; base += 16) {
        int idx = base + gl;
        int cl = 0; float wl = 0.f;
        if (idx < e) ntload(P, idx, &cl, &wl);
        int cnt = min(16, e - base);
        int j = 0;
        for (; j + 8 <= cnt; j += 8) {
            int   c0 = __shfl(cl, sb + j),     c1 = __shfl(cl, sb + j + 1);
            int   c2 = __shfl(cl, sb + j + 2), c3 = __shfl(cl, sb + j + 3);
            int   c4 = __shfl(cl, sb + j + 4), c5 = __shfl(cl, sb + j + 5);
            int   c6 = __shfl(cl, sb + j + 6), c7 = __shfl(cl, sb + j + 7);
            float w0 = __shfl(wl, sb + j),     w1 = __shfl(wl, sb + j + 1);
            float w2 = __shfl(wl, sb + j + 2), w3 = __shfl(wl, sb + j + 3);
            float w4 = __shfl(wl, sb + j + 4), w5 = __shfl(wl, sb + j + 5);
            float w6 = __shfl(wl, sb + j + 6), w7 = __shfl(wl, sb + j + 7);
            int u0 = (int)hF8[c0 * 16 + gl];
            int u1 = (int)hF8[c1 * 16 + gl];
            int u2 = (int)hF8[c2 * 16 + gl];
            int u3 = (int)hF8[c3 * 16 + gl];
            int u4 = (int)hF8[c4 * 16 + gl];
            int u5 = (int)hF8[c5 * 16 + gl];
            int u6 = (int)hF8[c6 * 16 + gl];
            int u7 = (int)hF8[c7 * 16 + gl];
            a0 += w0 * __builtin_amdgcn_cvt_f32_fp8(u0, 0);
            a1 += w0 * __builtin_amdgcn_cvt_f32_fp8(u0, 1);
            a2 += w0 * __builtin_amdgcn_cvt_f32_fp8(u0, 2);
            a3 += w0 * __builtin_amdgcn_cvt_f32_fp8(u0, 3);
            a0 += w1 * __builtin_amdgcn_cvt_f32_fp8(u1, 0);
            a1 += w1 * __builtin_amdgcn_cvt_f32_fp8(u1, 1);
            a2 += w1 * __builtin_amdgcn_cvt_f32_fp8(u1, 2);
            a3 += w1 * __builtin_amdgcn_cvt_f32_fp8(u1, 3);
            a0 += w2 * __builtin_amdgcn_cvt_f32_fp8(u2, 0);
            a1 += w2 * __builtin_amdgcn_cvt_f32_fp8(u2, 1);
            a2 += w2 * __builtin_amdgcn_cvt_f32_fp8(u2, 2);
            a3 += w2 * __builtin_amdgcn_cvt_f32_fp8(u2, 3);
            a0 += w3 * __builtin_amdgcn_cvt_f32_fp8(u3, 0);
            a1 += w3 * __builtin_amdgcn_cvt_f32_fp8(u3, 1);
            a2 += w3 * __builtin_amdgcn_cvt_f32_fp8(u3, 2);
            a3 += w3 * __builtin_amdgcn_cvt_f32_fp8(u3, 3);
            a0 += w4 * __builtin_amdgcn_cvt_f32_fp8(u4, 0);
            a1 += w4 * __builtin_amdgcn_cvt_f32_fp8(u4, 1);
            a2 += w4 * __builtin_amdgcn_cvt_f32_fp8(u4, 2);
            a3 += w4 * __builtin_amdgcn_cvt_f32_fp8(u4, 3);
            a0 += w5 * __builtin_amdgcn_cvt_f32_fp8(u5, 0);
            a1 += w5 * __builtin_amdgcn_cvt_f32_fp8(u5, 1);
            a2 += w5 * __builtin_amdgcn_cvt_f32_fp8(u5, 2);
            a3 += w5 * __builtin_amdgcn_cvt_f32_fp8(u5, 3);
            a0 += w6 * __builtin_amdgcn_cvt_f32_fp8(u6, 0);
            a1 += w6 * __builtin_amdgcn_cvt_f32_fp8(u6, 1);
            a2 += w6 * __builtin_amdgcn_cvt_f32_fp8(u6, 2);
            a3 += w6 * __builtin_amdgcn_cvt_f32_fp8(u6, 3);
            a0 += w7 * __builtin_amdgcn_cvt_f32_fp8(u7, 0);
            a1 += w7 * __builtin_amdgcn_cvt_f32_fp8(u7, 1);
            a2 += w7 * __builtin_amdgcn_cvt_f32_fp8(u7, 2);
            a3 += w7 * __builtin_amdgcn_cvt_f32_fp8(u7, 3);
        }
        for (; j < cnt; j++) {
            int   c = __shfl(cl, sb + j);
            float w = __shfl(wl, sb + j);
            int u = (int)hF8[c * 16 + gl];
            a0 += w * __builtin_amdgcn_cvt_f32_fp8(u, 0);
            a1 += w * __builtin_amdgcn_cvt_f32_fp8(u, 1);
            a2 += w * __builtin_amdgcn_cvt_f32_fp8(u, 2);
            a3 += w * __builtin_amdgcn_cvt_f32_fp8(u, 3);
        }
    }
    if (row < N)
        h2F8[row * 16 + gl] = fp8pack4(fmaxf(a0, 0.f), fmaxf(a1, 0.f),
                                       fmaxf(a2, 0.f), fmaxf(a3, 0.f));
}

// Shuffle-free, LDS-free dense: z = relu_h2 @ W2 + b2, fp8 out.
__global__ void dense_kernel(const unsigned* h2F8, const void* W2, const void* b2,
                             unsigned char* zb, const int* flags, int N) {
    int bf16 = flags[0];
    int wave = (int)((blockIdx.x * blockDim.x + threadIdx.x) >> 6);
    int lane = threadIdx.x & 63;
    int jj = (lane < LAB) ? lane : 0;
    float w2c[HID];
#pragma unroll
    for (int k = 0; k < HID; k++) w2c[k] = loadF(W2, (size_t)k * LAB + jj, bf16);
    float bias = loadF(b2, (size_t)jj, bf16);
    int r0 = wave * 32;
    int r1 = min(r0 + 32, N);
    for (int r = r0; r < r1; r++) {
        const unsigned* hr = h2F8 + (size_t)r * 16;
        float acc = bias;
#pragma unroll
        for (int k16 = 0; k16 < 16; k16++) {
            int d = (int)hr[k16];
            acc += __builtin_amdgcn_cvt_f32_fp8(d, 0) * w2c[4 * k16];
            acc += __builtin_amdgcn_cvt_f32_fp8(d, 1) * w2c[4 * k16 + 1];
            acc += __builtin_amdgcn_cvt_f32_fp8(d, 2) * w2c[4 * k16 + 2];
            acc += __builtin_amdgcn_cvt_f32_fp8(d, 3) * w2c[4 * k16 + 3];
        }
        if (lane < LAB) {
            int pk = __builtin_amdgcn_cvt_pk_fp8_f32(acc, acc, 0, false);
            zb[(size_t)r * LAB + lane] = (unsigned char)(pk & 0xFF);
        }
    }
}

// 4 rows/wave: z2 = A@z (fp8 gather), fused log_softmax -> out.
__global__ void gather_edge_lsm_kernel(const int* rp, const int2* P,
                                       const unsigned* zF8, void* out,
                                       const int* flags, int N) {
    int bf16 = flags[0];
    int wave = (blockIdx.x * blockDim.x + threadIdx.x) >> 6;
    int lane = threadIdx.x & 63;
    int g = lane >> 4, gl = lane & 15;
    int row = 4 * wave + g;
    int s = 0, e = 0;
    if (row < N) { s = rp[N + row]; e = rp[N + row + 1]; }
    float a0 = 0.f, a1 = 0.f, a2 = 0.f, a3 = 0.f;
    const int sb = g << 4;
    const int act = (gl < 10);
    for (int base = s; base < e; base += 16) {
        int idx = base + gl;
        int cl = 0; float wl = 0.f;
        if (idx < e) ntload(P, idx, &cl, &wl);
        int cnt = min(16, e - base);
        int j = 0;
        for (; j + 4 <= cnt; j += 4) {
            int   c0 = __shfl(cl, sb + j),     c1 = __shfl(cl, sb + j + 1);
            int   c2 = __shfl(cl, sb + j + 2), c3 = __shfl(cl, sb + j + 3);
            float w0 = __shfl(wl, sb + j),     w1 = __shfl(wl, sb + j + 1);
            float w2 = __shfl(wl, sb + j + 2), w3 = __shfl(wl, sb + j + 3);
            if (act) {
                int u0 = (int)zF8[c0 * 10 + gl];
                int u1 = (int)zF8[c1 * 10 + gl];
                int u2 = (int)zF8[c2 * 10 + gl];
                int u3 = (int)zF8[c3 * 10 + gl];
                a0 += w0 * __builtin_amdgcn_cvt_f32_fp8(u0, 0);
                a1 += w0 * __builtin_amdgcn_cvt_f32_fp8(u0, 1);
                a2 += w0 * __builtin_amdgcn_cvt_f32_fp8(u0, 2);
                a3 += w0 * __builtin_amdgcn_cvt_f32_fp8(u0, 3);
                a0 += w1 * __builtin_amdgcn_cvt_f32_fp8(u1, 0);
                a1 += w1 * __builtin_amdgcn_cvt_f32_fp8(u1, 1);
                a2 += w1 * __builtin_amdgcn_cvt_f32_fp8(u1, 2);
                a3 += w1 * __builtin_amdgcn_cvt_f32_fp8(u1, 3);
                a0 += w2 * __builtin_amdgcn_cvt_f32_fp8(u2, 0);
                a1 += w2 * __builtin_amdgcn_cvt_f32_fp8(u2, 1);
                a2 += w2 * __builtin_amdgcn_cvt_f32_fp8(u2, 2);
                a3 += w2 * __builtin_amdgcn_cvt_f32_fp8(u2, 3);
                a0 += w3 * __builtin_amdgcn_cvt_f32_fp8(u3, 0);
                a1 += w3 * __builtin_amdgcn_cvt_f32_fp8(u3, 1);
                a2 += w3 * __builtin_amdgcn_cvt_f32_fp8(u3, 2);
                a3 += w3 * __builtin_amdgcn_cvt_f32_fp8(u3, 3);
            }
        }
        for (; j < cnt; j++) {
            int   c = __shfl(cl, sb + j);
            float w = __shfl(wl, sb + j);
            if (act) {
                int u = (int)zF8[c * 10 + gl];
                a0 += w * __builtin_amdgcn_cvt_f32_fp8(u, 0);
                a1 += w * __builtin_amdgcn_cvt_f32_fp8(u, 1);
                a2 += w * __builtin_amdgcn_cvt_f32_fp8(u, 2);
                a3 += w * __builtin_amdgcn_cvt_f32_fp8(u, 3);
            }
        }
    }
    float m = act ? fmaxf(fmaxf(a0, a1), fmaxf(a2, a3)) : -INFINITY;
#pragma unroll
    for (int off = 8; off; off >>= 1) m = fmaxf(m, __shfl_xor(m, off));
    float es = act ? (__expf(a0 - m) + __expf(a1 - m) + __expf(a2 - m) + __expf(a3 - m)) : 0.f;
#pragma unroll
    for (int off = 8; off; off >>= 1) es += __shfl_xor(es, off);
    float lse = m + __logf(es);
    if (act && row < N) {
        float o0 = a0 - lse, o1 = a1 - lse, o2 = a2 - lse, o3 = a3 - lse;
        if (bf16) {
            ((uint2*)out)[(size_t)row * 10 + gl] =
                make_uint2(bfpack(o0, o1), bfpack(o2, o3));
        } else {
            float4 v = make_float4(o0, o1, o2, o3);
            ((float4*)out)[(size_t)row * 10 + gl] = v;
        }
    }
}

extern "C" void kernel_launch(void* const* d_in, const int* in_sizes, int n_in,
                              void* d_out, int out_size, void* d_ws, size_t ws_size,
                              hipStream_t stream) {
    const void* fidx = d_in[0];
    const void* fval = d_in[1];
    const void* eidx = d_in[2];
    const void* ew   = d_in[3];
    const void* W1   = d_in[4];
    const void* b1   = d_in[5];
    const void* W2   = d_in[6];
    const void* b2   = d_in[7];

    const int nnz = in_sizes[1];          // 2,500,000
    const int nW1 = in_sizes[4];          // 2048*64
    const int nE  = in_sizes[3];          // 1,700,000
    const int N   = out_size / LAB;       // 100,000
    const int M   = 2 * N;
    const int nT  = nnz + nE;
    const int K   = (M + (1 << RSH) - 1) >> RSH;   // 391 buckets

    auto align256 = [](size_t x) { return (x + 255) & ~(size_t)255; };
    char* ws = (char*)d_ws;
    size_t off = 0;
    int*   flags   = (int*)(ws + off);   off += 256;
    // front: hF8 (6.4MB) | h2F8 (6.4MB) | zF8 (4MB); Q (int2, 33.6MB) overlays
    // front and dies before gather_feat writes hF8.
    char*  front   = ws + off;
    unsigned* hF8  = (unsigned*)front;                       // N*16 dwords
    unsigned* h2F8 = hF8 + (size_t)N * 16;                   // N*16 dwords
    unsigned char* zb = (unsigned char*)(h2F8 + (size_t)N * 16);  // N*40 B
    size_t frontBytes = (size_t)N * (64 + 64 + 40);
    size_t qBytes     = (size_t)nT * 8;
    off += align256(frontBytes > qBytes ? frontBytes : qBytes);
    int2*  P       = (int2*)(ws + off);  off += align256((size_t)nT * 8);
    int*   rp      = (int*)(ws + off);   off += align256(((size_t)KMAX << RSH) * 4 + 16);
    uint2* w1q     = (uint2*)(ws + off); off += align256((size_t)nW1 * 2);
    int*   cntB    = (int*)(ws + off);   off += KMAX * 4;
    int*   bqstart = (int*)(ws + off);   off += KMAX * 4;
    int*   bq      = (int*)(ws + off);   off += KMAX * 4;
    int2*  Q       = (int2*)front;

    // 1. dtype probe
    probe_kernel<<<1, 64, 0, stream>>>(b1, fidx, flags);

    // 2. zero bucket histogram; stage W1 packed
    zero_kernel<<<1, 256, 0, stream>>>((int4*)cntB, KMAX / 4);
    convw1_kernel<<<(nW1 / 4 + 255) / 256, 256, 0, stream>>>(W1, w1q, flags, nW1 / 4);

    // 3. bucket histogram (LDS-privatized)
    const int HB = 1024;
    histB_kernel<<<HB, 256, 0, stream>>>(fidx, eidx, cntB, flags, nnz, nE, N, HB);

    // 4. bucket scan -> starts + cursors
    scanB_kernel<<<1, KMAX, 0, stream>>>(cntB, bqstart, bq, K);

    // 5. pass A: bucket-grouped scatter into Q (16384-elem tiles, rank-free)
    bucketA_kernel<<<(nT + TILE_A - 1) / TILE_A, 512, 0, stream>>>(
        fidx, fval, eidx, ew, flags, bq, Q, nnz, nE, N);

    // 6. pass B: per-bucket row hist/scan in LDS, rp segment, scatter -> P
    bucketB_kernel<<<K, 512, 0, stream>>>(Q, bqstart, rp, P, nT, K);

    // 7. h = sparse_features @ W1 + b1 -> fp8
    int nwaves = (N + 3) / 4;
    int gblocks = (int)(((size_t)nwaves * 64 + 255) / 256);
    gather_feat_kernel<<<gblocks, 256, 0, stream>>>(rp, P, w1q, b1, hF8, flags, N);

    // 8. h2 = relu(A @ h) -> fp8 (gather-only, no epilogue)
    gather_edge_h2_kernel<<<gblocks, 256, 0, stream>>>(rp, P, hF8, h2F8, N);

    // 9. z = h2 @ W2 + b2 -> fp8 (shuffle-free dense)
    int dwaves = (N + 31) / 32;
    int dblocks = (dwaves * 64 + 255) / 256;
    dense_kernel<<<dblocks, 256, 0, stream>>>(h2F8, W2, b2, zb, flags, N);

    // 10. out = log_softmax(A @ z)
    gather_edge_lsm_kernel<<<gblocks, 256, 0, stream>>>(rp, P, (const unsigned*)zb,
                                                        d_out, flags, N);
}